// Round 1
// baseline (474.236 us; speedup 1.0000x reference)
//
#include <hip/hip_runtime.h>
#include <hip/hip_bf16.h>

// ---------------------------------------------------------------------------
// SpatialAttention — ROUND 10 (= R9 + k_attn swapped-operand restructure).
//  * k_attn: S^T = MFMA(K,Q) so each lane owns ONE query (l16) -> per-lane
//    scalar m/l, 2-shuffle row-max, no cross-lane rescale/divide.
//    P feeds PV directly as B-fragment (V stored k-slot-permuted in k_norm_kv)
//    -> pbuf LDS roundtrip deleted. O computed transposed (O^T = V^T P^T),
//    redistributed with an 8-shuffle butterfly before a 16B coalesced store.
//    Chunked online softmax (64-key chunks, s[4]) + 0.5*log2e folded into the
//    q-channel BN scale -> base-2 exp (bare v_exp_f32), mask = bfe+cndmask.
//    VGPR target <=128 (launch_bounds(256,4)) + LDS 32KB -> 4 blocks/CU,
//    grid 1536 (q-quarters, XCD-local per bh).
//  * everything else identical to R9.
// Sizes: BT=96, N=512, D=128, heads=4, hd=32, RR=49152. Biases cancel in BN.
// ---------------------------------------------------------------------------

#define BT   96
#define NN   512
#define DD   128
#define CIN  256
#define CQKV 384
#define RR   49152
#define EPSB 1e-5f

using bf16  = __hip_bfloat16;
using bf8_t = __attribute__((ext_vector_type(8))) short;   // 8 x bf16
using f32x4 = __attribute__((ext_vector_type(4))) float;
using u32x4 = __attribute__((ext_vector_type(4))) unsigned int;

#define MFMA16(a,b,c) __builtin_amdgcn_mfma_f32_16x16x32_bf16((a),(b),(c),0,0,0)

__device__ __forceinline__ short f2b(float f) {
  bf16 h = __float2bfloat16(f);
  return *reinterpret_cast<short*>(&h);
}
__device__ __forceinline__ float b2f(short s) {
  bf16 h; *reinterpret_cast<short*>(&h) = s;
  return __bfloat162float(h);
}
__device__ __forceinline__ float fexp2(float x) {
#if __has_builtin(__builtin_amdgcn_exp2f)
  return __builtin_amdgcn_exp2f(x);
#else
  return exp2f(x);
#endif
}
__device__ __forceinline__ unsigned int pk2(float lo, float hi) {
  return (unsigned int)(unsigned short)f2b(lo) |
         ((unsigned int)(unsigned short)f2b(hi) << 16);
}
__device__ __forceinline__ void gl_lds16(const void* g, void* l) {
  __builtin_amdgcn_global_load_lds(
      (const __attribute__((address_space(1))) unsigned int*)g,
      (__attribute__((address_space(3))) unsigned int*)l, 16, 0, 0);
}

// ------------------- prep: W transpose + mask bitmask + zero stats ---------
// Work items: 98304 (Wtq) + 16384 (Wto) + 8192 (Amb) + 1024 (st) = 123904
// -> grid 484 x 256.
__global__ __launch_bounds__(256) void k_prep(
    const float* __restrict__ Wq, const float* __restrict__ Wk,
    const float* __restrict__ Wv, const float* __restrict__ Wo,
    const float* __restrict__ Am,
    bf16* __restrict__ Wtq, bf16* __restrict__ Wto,
    unsigned int* __restrict__ Amb, float* __restrict__ st)
{
  int idx = blockIdx.x * 256 + threadIdx.x;
  if (idx < CQKV * CIN) {                          // Wtq[c][k] = W[k][c]
    int c = idx >> 8;
    int k = idx & 255;
    const float* W = (c < 128) ? Wq : ((c < 256) ? Wk : Wv);
    int cl = c & 127;
    Wtq[idx] = __float2bfloat16(W[(size_t)k * 128 + cl]);
  } else if (idx < CQKV * CIN + 128 * 128) {       // Wto[c][k] = Wo[k][c]
    int j = idx - CQKV * CIN;
    int c = j >> 7, k = j & 127;
    Wto[j] = __float2bfloat16(Wo[(size_t)k * 128 + c]);
  } else if (idx < CQKV * CIN + 128 * 128 + 8192) {  // Amb[n][l16] bit mt
    int j = idx - (CQKV * CIN + 128 * 128);
    int l16 = j & 15, n = j >> 4;
    unsigned int w = 0;
#pragma unroll
    for (int mt = 0; mt < 32; ++mt)
      if (Am[(size_t)n * NN + mt * 16 + l16] > 0.f) w |= (1u << mt);
    Amb[j] = w;
  } else if (idx < CQKV * CIN + 128 * 128 + 8192 + 1024) {
    st[idx - (CQKV * CIN + 128 * 128 + 8192)] = 0.f;
  }
}

// ------------------- QKV GEMM + fused stats --------------------------------
// grid (384,3); 128x128 tile, BK=32; A fp32 via global_load_lds (swizzled).
__global__ __launch_bounds__(256) void k_gemm_qkv(
    const float* __restrict__ X, const float* __restrict__ STE,
    const bf16* __restrict__ Wt, bf16* __restrict__ Y, float* __restrict__ st)
{
  __shared__ __align__(16) float As[128 * 32];
  __shared__ __align__(16) bf16  Bs[128 * 32];
  int tid = threadIdx.x;
  int lane = tid & 63;
  int wave = tid >> 6;
  int quad = lane >> 4, l16 = lane & 15;
  int wm = wave & 1, wn = wave >> 1;
  int row0 = blockIdx.x * 128;
  int col0 = blockIdx.y * 128;

  f32x4 acc[4][4] = {};

  for (int kb = 0; kb < 256; kb += 32) {
    const float* Abase = (kb < 128) ? (X + (size_t)row0 * 128 + kb)
                                    : (STE + (size_t)row0 * 128 + (kb - 128));
    __syncthreads();
#pragma unroll
    for (int j = 0; j < 4; ++j) {
      int slot = tid + 256 * j;
      int r = slot >> 3, s = slot & 7;
      int p = s ^ (r & 7);
      gl_lds16(Abase + (size_t)r * 128 + p * 4, (char*)As + slot * 16);
    }
#pragma unroll
    for (int j = 0; j < 2; ++j) {
      int slot = tid + 256 * j;
      int r = slot >> 2, s = slot & 3;
      int p = s ^ ((r >> 1) & 3);
      gl_lds16(Wt + (size_t)(col0 + r) * CIN + kb + p * 8, (char*)Bs + slot * 16);
    }
    __syncthreads();

    bf8_t afr[4];
#pragma unroll
    for (int mi = 0; mi < 4; ++mi) {
      int r = wm * 64 + mi * 16 + l16;
      int s0 = (2 * quad) ^ (r & 7);
      f32x4 a0 = *reinterpret_cast<const f32x4*>(&As[r * 32 + s0 * 4]);
      f32x4 a1 = *reinterpret_cast<const f32x4*>(&As[r * 32 + (s0 ^ 1) * 4]);
      afr[mi] = bf8_t{ f2b(a0[0]), f2b(a0[1]), f2b(a0[2]), f2b(a0[3]),
                       f2b(a1[0]), f2b(a1[1]), f2b(a1[2]), f2b(a1[3]) };
    }
#pragma unroll
    for (int ni = 0; ni < 4; ++ni) {
      int c = wn * 64 + ni * 16 + l16;
      int sB = quad ^ ((c >> 1) & 3);
      bf8_t bfr = *reinterpret_cast<const bf8_t*>(&Bs[c * 32 + sB * 8]);
#pragma unroll
      for (int mi = 0; mi < 4; ++mi)
        acc[mi][ni] = MFMA16(afr[mi], bfr, acc[mi][ni]);
    }
  }
#pragma unroll
  for (int mi = 0; mi < 4; ++mi)
#pragma unroll
    for (int ni = 0; ni < 4; ++ni)
#pragma unroll
      for (int rr = 0; rr < 4; ++rr) {
        int row = row0 + wm * 64 + mi * 16 + quad * 4 + rr;
        int col = col0 + wn * 64 + ni * 16 + l16;
        Y[(size_t)row * CQKV + col] = __float2bfloat16(acc[mi][ni][rr]);
      }
  // fused per-channel stats: wave covers 64 rows of each of its 64 cols
#pragma unroll
  for (int ni = 0; ni < 4; ++ni) {
    float sp = 0.f, qp = 0.f;
#pragma unroll
    for (int mi = 0; mi < 4; ++mi)
#pragma unroll
      for (int rr = 0; rr < 4; ++rr) {
        float v = acc[mi][ni][rr];
        sp += v; qp += v * v;
      }
    sp += __shfl_xor(sp, 16); sp += __shfl_xor(sp, 32);
    qp += __shfl_xor(qp, 16); qp += __shfl_xor(qp, 32);
    if (quad == 0) {
      int c = col0 + wn * 64 + ni * 16 + l16;
      atomicAdd(&st[c], sp);
      atomicAdd(&st[CQKV + c], qp);
    }
  }
}

// ------------------- out GEMM (fp32 out) + fused stats ---------------------
__global__ __launch_bounds__(256) void k_gemm_o(
    const bf16* __restrict__ AO, const bf16* __restrict__ Wto,
    float* __restrict__ Yo, float* __restrict__ st)
{
  __shared__ __align__(16) bf16 As[128 * 32];
  __shared__ __align__(16) bf16 Bs[128 * 32];
  int tid = threadIdx.x;
  int lane = tid & 63;
  int wave = tid >> 6;
  int quad = lane >> 4, l16 = lane & 15;
  int wm = wave & 1, wn = wave >> 1;
  int row0 = blockIdx.x * 128;

  f32x4 acc[4][4] = {};

  for (int kb = 0; kb < 128; kb += 32) {
    __syncthreads();
#pragma unroll
    for (int j = 0; j < 2; ++j) {
      int slot = tid + 256 * j;
      int r = slot >> 2, s = slot & 3;
      int p = s ^ ((r >> 1) & 3);
      gl_lds16(AO + (size_t)(row0 + r) * 128 + kb + p * 8, (char*)As + slot * 16);
    }
#pragma unroll
    for (int j = 0; j < 2; ++j) {
      int slot = tid + 256 * j;
      int r = slot >> 2, s = slot & 3;
      int p = s ^ ((r >> 1) & 3);
      gl_lds16(Wto + (size_t)r * 128 + kb + p * 8, (char*)Bs + slot * 16);
    }
    __syncthreads();

    bf8_t afr[4];
#pragma unroll
    for (int mi = 0; mi < 4; ++mi) {
      int r = wm * 64 + mi * 16 + l16;
      int sA = quad ^ ((r >> 1) & 3);
      afr[mi] = *reinterpret_cast<const bf8_t*>(&As[r * 32 + sA * 8]);
    }
#pragma unroll
    for (int ni = 0; ni < 4; ++ni) {
      int c = wn * 64 + ni * 16 + l16;
      int sB = quad ^ ((c >> 1) & 3);
      bf8_t bfr = *reinterpret_cast<const bf8_t*>(&Bs[c * 32 + sB * 8]);
#pragma unroll
      for (int mi = 0; mi < 4; ++mi)
        acc[mi][ni] = MFMA16(afr[mi], bfr, acc[mi][ni]);
    }
  }
#pragma unroll
  for (int mi = 0; mi < 4; ++mi)
#pragma unroll
    for (int ni = 0; ni < 4; ++ni)
#pragma unroll
      for (int rr = 0; rr < 4; ++rr) {
        int row = row0 + wm * 64 + mi * 16 + quad * 4 + rr;
        int col = wn * 64 + ni * 16 + l16;
        Yo[(size_t)row * 128 + col] = acc[mi][ni][rr];
      }
#pragma unroll
  for (int ni = 0; ni < 4; ++ni) {
    float sp = 0.f, qp = 0.f;
#pragma unroll
    for (int mi = 0; mi < 4; ++mi)
#pragma unroll
      for (int rr = 0; rr < 4; ++rr) {
        float v = acc[mi][ni][rr];
        sp += v; qp += v * v;
      }
    sp += __shfl_xor(sp, 16); sp += __shfl_xor(sp, 32);
    qp += __shfl_xor(qp, 16); qp += __shfl_xor(qp, 32);
    if (quad == 0) {
      int c = wn * 64 + ni * 16 + l16;
      atomicAdd(&st[c], sp);
      atomicAdd(&st[128 + c], qp);
    }
  }
}

// ------------------- BN scale/shift for the 384 qkv channels ---------------
// q channels (c<128) additionally fold 0.5*log2(e): attention score scale
// 1/sqrt(d)=0.5 and e->2 exponent base (relu commutes with positive scale).
__global__ void k_scales_qkv(const float* __restrict__ st,
                             const float* __restrict__ gq, const float* __restrict__ beq,
                             const float* __restrict__ gk, const float* __restrict__ bek,
                             const float* __restrict__ gv, const float* __restrict__ bev,
                             float* __restrict__ scv, float* __restrict__ shv)
{
  int c = threadIdx.x;
  const float inv = 1.0f / (float)RR;
  float mu  = st[c] * inv;
  float var = st[CQKV + c] * inv - mu * mu;
  const float *g, *be; int cl = c;
  if (c < 128)      { g = gq; be = beq; }
  else if (c < 256) { g = gk; be = bek; cl = c - 128; }
  else              { g = gv; be = bev; cl = c - 256; }
  float sc = g[cl] * rsqrtf(var + EPSB);
  float sh = be[cl] - mu * sc;
  if (c < 128) { sc *= 0.7213475204444817f; sh *= 0.7213475204444817f; }
  scv[c] = sc;
  shv[c] = sh;
}

// ------------------- norm+ReLU: K rows + V (permuted A-layout) -------------
// grid (384, 8). Kh: [bh][n][kk] row-major.
// Vt[bh][dim(32)][kc(16)][quad(4)][j(8)] : element =
//   V[key = kc*32 + (j>>2)*16 + quad*4 + (j&3)][dim]
// -> matches P's natural register order in k_attn (k-slot permutation of the
//    MFMA contraction, applied consistently to A (V^T) and B (P^T)).
__global__ __launch_bounds__(256) void k_norm_kv(
    const bf16* __restrict__ Y, const float* __restrict__ scv,
    const float* __restrict__ shv, bf16* __restrict__ Kh, bf16* __restrict__ Vt)
{
  __shared__ short vs[64][40];
  int t = threadIdx.x;
  int bh = blockIdx.x, nc = blockIdx.y;
  int bt = bh >> 2, h = bh & 3;
  int n0 = nc * 64;
  int r = t >> 2, cg = t & 3;
  // ---- K phase
  {
    int c = 128 + h * 32 + cg * 8;
    bf8_t y8 = *reinterpret_cast<const bf8_t*>(
        Y + ((size_t)bt * NN + n0 + r) * CQKV + c);
    short o8[8];
#pragma unroll
    for (int i = 0; i < 8; ++i)
      o8[i] = f2b(fmaxf(0.f, fmaf(b2f(y8[i]), scv[c + i], shv[c + i])));
    *reinterpret_cast<bf8_t*>(Kh + ((size_t)bh * NN + n0 + r) * 32 + cg * 8) =
        *reinterpret_cast<bf8_t*>(o8);
  }
  // ---- V phase (LDS transpose into permuted A-layout)
  {
    int c = 256 + h * 32 + cg * 8;
    bf8_t y8 = *reinterpret_cast<const bf8_t*>(
        Y + ((size_t)bt * NN + n0 + r) * CQKV + c);
    short o8[8];
#pragma unroll
    for (int i = 0; i < 8; ++i)
      o8[i] = f2b(fmaxf(0.f, fmaf(b2f(y8[i]), scv[c + i], shv[c + i])));
    *reinterpret_cast<bf8_t*>(&vs[r][cg * 8]) = *reinterpret_cast<bf8_t*>(o8);
  }
  __syncthreads();
  int dim = t >> 3, kcl = (t >> 2) & 1, quad = t & 3;
  short w8[8];
#pragma unroll
  for (int j = 0; j < 8; ++j)
    w8[j] = vs[kcl * 32 + (j >> 2) * 16 + quad * 4 + (j & 3)][dim];
  *reinterpret_cast<bf8_t*>(Vt + (size_t)bh * 16384 + (size_t)dim * 512 +
                            (nc * 2 + kcl) * 32 + quad * 8) =
      *reinterpret_cast<bf8_t*>(w8);
}

// ------------------- fused masked attention (swapped operands) -------------
// grid 1536: bh = x % 384 (XCD-local), quarter = x / 384 (8 q-tiles each).
// S^T = MFMA(K, Q): lane owns query l16; per-lane scalar online softmax over
// 8 chunks of 64 keys; P -> PV B-fragment directly (V pre-permuted);
// O^T = MFMA(V^T, P^T); butterfly-redistribute O for a 16B coalesced store.
__global__ __launch_bounds__(256, 4) void k_attn(
    const bf16* __restrict__ Y, const float* __restrict__ scv,
    const float* __restrict__ shv, const bf16* __restrict__ Kh,
    const bf16* __restrict__ Vt, const unsigned int* __restrict__ Amb,
    bf16* __restrict__ AO)
{
  __shared__ __align__(16) bf16 KbS[512 * 32];     // 32 KB, rows 64B swizzled
  int tid = threadIdx.x;
  int wave = tid >> 6, lane = tid & 63;
  int quad = lane >> 4, l16 = lane & 15;
  int bh = blockIdx.x % 384;
  int quarter = blockIdx.x / 384;                  // q-tile quarter (0..3)
  int bt = bh >> 2, h = bh & 3;
  const char* Kp = (const char*)(Kh + (size_t)bh * NN * 32);
  const bf16* Vp = Vt + (size_t)bh * NN * 32;

  // ---- stage K with row-chunk swizzle
#pragma unroll
  for (int i = 0; i < 8; ++i) {
    int t2 = wave * 8 + i;
    int r = t2 * 16 + (lane >> 2);
    int p = (lane & 3) ^ ((r >> 1) & 3);
    gl_lds16(Kp + (size_t)r * 64 + p * 16, (char*)KbS + t2 * 1024 + lane * 16);
  }
  __syncthreads();

  const f32x4 zero = {0.f, 0.f, 0.f, 0.f};
#pragma unroll 1
  for (int it = 0; it < 2; ++it) {
    int nt = quarter * 8 + it * 4 + wave;          // global ntile 0..31
    int n0 = nt * 16;
    // Q inline norm+ReLU from Y: B-fragment (col=query l16, k=dim quad*8+j)
    int cq = h * 32 + quad * 8;
    bf8_t yq = *reinterpret_cast<const bf8_t*>(
        Y + ((size_t)bt * NN + n0 + l16) * CQKV + cq);
    bf8_t qf;
#pragma unroll
    for (int j = 0; j < 8; ++j)
      qf[j] = f2b(fmaxf(0.f, fmaf(b2f(yq[j]), scv[cq + j], shv[cq + j])));
    // mask words: query n0+l16, key-lane quad*4+rr, bit index = key tile
    unsigned int wm[4];
#pragma unroll
    for (int rr = 0; rr < 4; ++rr)
      wm[rr] = Amb[(size_t)(n0 + l16) * 16 + quad * 4 + rr];

    f32x4 o0 = zero, o1 = zero;                    // O^T dims 0-15 / 16-31
    float mrun = 0.f, lrun = 0.f;                  // valid: scores >= 0

#pragma unroll
    for (int c = 0; c < 8; ++c) {
      // S^T chunk: 4 tiles x 16 keys; lane = (key quad*4+rr, query l16)
      f32x4 s[4];
#pragma unroll
      for (int mt = 0; mt < 4; ++mt) {
        int r = (c * 4 + mt) * 16 + l16;
        bf8_t kf = *reinterpret_cast<const bf8_t*>(
            (const char*)KbS + (size_t)r * 64 + ((quad ^ ((r >> 1) & 3)) * 16));
        s[mt] = MFMA16(kf, qf, zero);
      }
      // mask + chunk max (scale already folded into qf)
      float lmax = -1e30f;
#pragma unroll
      for (int mt = 0; mt < 4; ++mt)
#pragma unroll
        for (int rr = 0; rr < 4; ++rr) {
          float v = ((wm[rr] >> (c * 4 + mt)) & 1u) ? s[mt][rr] : -1e30f;
          s[mt][rr] = v;
          lmax = fmaxf(lmax, v);
        }
      lmax = fmaxf(lmax, __shfl_xor(lmax, 16));
      lmax = fmaxf(lmax, __shfl_xor(lmax, 32));
      float mnew = fmaxf(mrun, lmax);
      float alpha = fexp2(mrun - mnew);
      mrun = mnew;
      lrun *= alpha;
#pragma unroll
      for (int rr = 0; rr < 4; ++rr) { o0[rr] *= alpha; o1[rr] *= alpha; }
      // exp2 + partial sum + pack into PV B-fragments (natural order!)
      short p0[8], p1[8];
      float ls = 0.f;
#pragma unroll
      for (int mt = 0; mt < 2; ++mt)
#pragma unroll
        for (int rr = 0; rr < 4; ++rr) {
          float p = fexp2(s[mt][rr] - mnew);
          ls += p;
          p0[mt * 4 + rr] = f2b(p);
        }
#pragma unroll
      for (int mt = 2; mt < 4; ++mt)
#pragma unroll
        for (int rr = 0; rr < 4; ++rr) {
          float p = fexp2(s[mt][rr] - mnew);
          ls += p;
          p1[(mt - 2) * 4 + rr] = f2b(p);
        }
      lrun += ls;
      bf8_t f0 = *reinterpret_cast<bf8_t*>(p0);
      bf8_t f1 = *reinterpret_cast<bf8_t*>(p1);
      // PV: O^T += V^T_chunk . P^T_chunk   (V pre-permuted to P's k-order)
      const bf16* va = Vp + (size_t)l16 * 512 + c * 64 + quad * 8;
      o0 = MFMA16(*reinterpret_cast<const bf8_t*>(va),        f0, o0);
      o0 = MFMA16(*reinterpret_cast<const bf8_t*>(va + 32),   f1, o0);
      o1 = MFMA16(*reinterpret_cast<const bf8_t*>(va + 8192), f0, o1);
      o1 = MFMA16(*reinterpret_cast<const bf8_t*>(va + 8224), f1, o1);
    }
    // final: per-lane partial sums -> cross-quad total, divide (lane-local)
    lrun += __shfl_xor(lrun, 16);
    lrun += __shfl_xor(lrun, 32);
    float inv = 1.0f / lrun;
    unsigned int w0 = pk2(o0[0] * inv, o0[1] * inv);   // dims q*4+0, +1
    unsigned int w1 = pk2(o0[2] * inv, o0[3] * inv);   // dims q*4+2, +3
    unsigned int w2 = pk2(o1[0] * inv, o1[1] * inv);   // dims 16+q*4+0, +1
    unsigned int w3 = pk2(o1[2] * inv, o1[3] * inv);
    // butterfly: lane(quad,l16) gathers dims quad*8..+7 of its query l16
    int sL0 = (quad & 1) * 32 + l16;
    int sL1 = sL0 + 16;
    bool hi = quad >= 2;
    unsigned int a0 = __shfl(w0, sL0), b0 = __shfl(w2, sL0);
    unsigned int a1 = __shfl(w1, sL0), b1 = __shfl(w3, sL0);
    unsigned int a2 = __shfl(w0, sL1), b2 = __shfl(w2, sL1);
    unsigned int a3 = __shfl(w1, sL1), b3 = __shfl(w3, sL1);
    u32x4 ov = { hi ? b0 : a0, hi ? b1 : a1, hi ? b2 : a2, hi ? b3 : a3 };
    *reinterpret_cast<u32x4*>(
        AO + ((size_t)bt * NN + n0 + l16) * DD + h * 32 + quad * 8) = ov;
  }
}

// ------------------- final BN + ReLU ---------------------------------------
__global__ __launch_bounds__(256) void k_norm_o(
    const float* __restrict__ Yo, const float* __restrict__ st,
    const float* __restrict__ g, const float* __restrict__ be,
    float* __restrict__ out)
{
  int idx = blockIdx.x * 256 + threadIdx.x;      // < RR*128
  int c = idx & 127;
  const float inv = 1.0f / (float)RR;
  float mu  = st[c] * inv;
  float var = st[128 + c] * inv - mu * mu;
  float sc = g[c] * rsqrtf(var + EPSB);
  float sh = be[c] - mu * sc;
  out[idx] = fmaxf(0.f, fmaf(Yo[idx], sc, sh));
}

// ---------------------------------------------------------------------------
extern "C" void kernel_launch(void* const* d_in, const int* in_sizes, int n_in,
                              void* d_out, int out_size, void* d_ws, size_t ws_size,
                              hipStream_t stream)
{
  const float* X    = (const float*)d_in[0];
  const float* STE  = (const float*)d_in[1];
  const float* Am   = (const float*)d_in[2];
  const float* Wq   = (const float*)d_in[3];
  const float* gq   = (const float*)d_in[5];
  const float* beq  = (const float*)d_in[6];
  const float* Wk   = (const float*)d_in[7];
  const float* gk   = (const float*)d_in[9];
  const float* bek  = (const float*)d_in[10];
  const float* Wv   = (const float*)d_in[11];
  const float* gv   = (const float*)d_in[13];
  const float* bev  = (const float*)d_in[14];
  const float* Wo   = (const float*)d_in[15];
  const float* go   = (const float*)d_in[17];
  const float* beo  = (const float*)d_in[18];
  // biases d_in[4,8,12,16] unused: BN subtracts batch mean -> bias cancels.

  char* ws = (char*)d_ws;
  bf16*  Yqkv = (bf16*)(ws + 0);            // 37,748,736
  float* Yo   = (float*)(ws + 0);           // aliases Yqkv (dead after attn)
  bf16*  Kh   = (bf16*)(ws + 50331648);
  bf16*  Vt   = (bf16*)(ws + 62914560);
  bf16*  AO   = (bf16*)(ws + 75497472);
  bf16*  Wtq  = (bf16*)(ws + 88080384);     // 196,608
  bf16*  Wto  = (bf16*)(ws + 88276992);     // 32,768
  unsigned int* Amb = (unsigned int*)(ws + 88309760);  // 32,768
  float* st   = (float*)(ws + 88342528);    // [0,768) qkv | [768,1024) o
  float* stq  = st;
  float* sto  = st + 768;
  float* scv  = st + 1024;
  float* shv  = st + 1408;

  k_prep<<<484, 256, 0, stream>>>(Wq, Wk, Wv, Wo, Am, Wtq, Wto, Amb, st);
  k_gemm_qkv<<<dim3(RR / 128, 3), 256, 0, stream>>>(X, STE, Wtq, Yqkv, stq);
  k_scales_qkv<<<1, CQKV, 0, stream>>>(stq, gq, beq, gk, bek, gv, bev, scv, shv);
  k_norm_kv<<<dim3(CQKV, 8), 256, 0, stream>>>(Yqkv, scv, shv, Kh, Vt);
  k_attn<<<1536, 256, 0, stream>>>(Yqkv, scv, shv, Kh, Vt, Amb, AO);
  k_gemm_o<<<dim3(RR / 128, 1), 256, 0, stream>>>(AO, Wto, Yo, sto);
  k_norm_o<<<(RR * 128) / 256, 256, 0, stream>>>(Yo, sto, go, beo, (float*)d_out);
}

// Round 2
// 470.893 us; speedup vs baseline: 1.0071x; 1.0071x over previous
//
#include <hip/hip_runtime.h>
#include <hip/hip_bf16.h>

// ---------------------------------------------------------------------------
// SpatialAttention — ROUND 11 (= R10 with the scratch spill fixed + coalesced
// V layout).
//  * R10's regression root-cause: short p0[8]/p1[8] staging arrays read back
//    through reinterpret_cast -> address taken -> scratch (390 MB fetch +
//    361 MB write of spill traffic in k_attn). Fixed by building the PV
//    B-fragments as bf8_t vector-element inserts (constant indices only).
//    Same treatment for o8[]/w8[] in k_norm_kv.
//  * Vt re-ordered chunk-major: [bh][cidx(16)][dim(32)][quad(4)][j(8)] so each
//    PV A-fragment load is one fully-coalesced 1 KB wave access (R10's
//    [dim][key] layout scattered 64 lanes over 1 KB-strided rows).
//  * Everything else identical to R10: S^T = MFMA(K,Q) lane-owns-query
//    softmax, base-2 exp with 0.5*log2e folded into q-channel BN, butterfly
//    O redistribution, grid 1536, LDS 32 KB.
// Sizes: BT=96, N=512, D=128, heads=4, hd=32, RR=49152. Biases cancel in BN.
// ---------------------------------------------------------------------------

#define BT   96
#define NN   512
#define DD   128
#define CIN  256
#define CQKV 384
#define RR   49152
#define EPSB 1e-5f

using bf16  = __hip_bfloat16;
using bf8_t = __attribute__((ext_vector_type(8))) short;   // 8 x bf16
using f32x4 = __attribute__((ext_vector_type(4))) float;
using u32x4 = __attribute__((ext_vector_type(4))) unsigned int;

#define MFMA16(a,b,c) __builtin_amdgcn_mfma_f32_16x16x32_bf16((a),(b),(c),0,0,0)

__device__ __forceinline__ short f2b(float f) {
  bf16 h = __float2bfloat16(f);
  return *reinterpret_cast<short*>(&h);
}
__device__ __forceinline__ float b2f(short s) {
  bf16 h; *reinterpret_cast<short*>(&h) = s;
  return __bfloat162float(h);
}
__device__ __forceinline__ float fexp2(float x) {
#if __has_builtin(__builtin_amdgcn_exp2f)
  return __builtin_amdgcn_exp2f(x);
#else
  return exp2f(x);
#endif
}
__device__ __forceinline__ unsigned int pk2(float lo, float hi) {
  return (unsigned int)(unsigned short)f2b(lo) |
         ((unsigned int)(unsigned short)f2b(hi) << 16);
}
__device__ __forceinline__ void gl_lds16(const void* g, void* l) {
  __builtin_amdgcn_global_load_lds(
      (const __attribute__((address_space(1))) unsigned int*)g,
      (__attribute__((address_space(3))) unsigned int*)l, 16, 0, 0);
}

// ------------------- prep: W transpose + mask bitmask + zero stats ---------
// Work items: 98304 (Wtq) + 16384 (Wto) + 8192 (Amb) + 1024 (st) = 123904
// -> grid 484 x 256.
__global__ __launch_bounds__(256) void k_prep(
    const float* __restrict__ Wq, const float* __restrict__ Wk,
    const float* __restrict__ Wv, const float* __restrict__ Wo,
    const float* __restrict__ Am,
    bf16* __restrict__ Wtq, bf16* __restrict__ Wto,
    unsigned int* __restrict__ Amb, float* __restrict__ st)
{
  int idx = blockIdx.x * 256 + threadIdx.x;
  if (idx < CQKV * CIN) {                          // Wtq[c][k] = W[k][c]
    int c = idx >> 8;
    int k = idx & 255;
    const float* W = (c < 128) ? Wq : ((c < 256) ? Wk : Wv);
    int cl = c & 127;
    Wtq[idx] = __float2bfloat16(W[(size_t)k * 128 + cl]);
  } else if (idx < CQKV * CIN + 128 * 128) {       // Wto[c][k] = Wo[k][c]
    int j = idx - CQKV * CIN;
    int c = j >> 7, k = j & 127;
    Wto[j] = __float2bfloat16(Wo[(size_t)k * 128 + c]);
  } else if (idx < CQKV * CIN + 128 * 128 + 8192) {  // Amb[n][l16] bit mt
    int j = idx - (CQKV * CIN + 128 * 128);
    int l16 = j & 15, n = j >> 4;
    unsigned int w = 0;
#pragma unroll
    for (int mt = 0; mt < 32; ++mt)
      if (Am[(size_t)n * NN + mt * 16 + l16] > 0.f) w |= (1u << mt);
    Amb[j] = w;
  } else if (idx < CQKV * CIN + 128 * 128 + 8192 + 1024) {
    st[idx - (CQKV * CIN + 128 * 128 + 8192)] = 0.f;
  }
}

// ------------------- QKV GEMM + fused stats --------------------------------
// grid (384,3); 128x128 tile, BK=32; A fp32 via global_load_lds (swizzled).
__global__ __launch_bounds__(256) void k_gemm_qkv(
    const float* __restrict__ X, const float* __restrict__ STE,
    const bf16* __restrict__ Wt, bf16* __restrict__ Y, float* __restrict__ st)
{
  __shared__ __align__(16) float As[128 * 32];
  __shared__ __align__(16) bf16  Bs[128 * 32];
  int tid = threadIdx.x;
  int lane = tid & 63;
  int wave = tid >> 6;
  int quad = lane >> 4, l16 = lane & 15;
  int wm = wave & 1, wn = wave >> 1;
  int row0 = blockIdx.x * 128;
  int col0 = blockIdx.y * 128;

  f32x4 acc[4][4] = {};

  for (int kb = 0; kb < 256; kb += 32) {
    const float* Abase = (kb < 128) ? (X + (size_t)row0 * 128 + kb)
                                    : (STE + (size_t)row0 * 128 + (kb - 128));
    __syncthreads();
#pragma unroll
    for (int j = 0; j < 4; ++j) {
      int slot = tid + 256 * j;
      int r = slot >> 3, s = slot & 7;
      int p = s ^ (r & 7);
      gl_lds16(Abase + (size_t)r * 128 + p * 4, (char*)As + slot * 16);
    }
#pragma unroll
    for (int j = 0; j < 2; ++j) {
      int slot = tid + 256 * j;
      int r = slot >> 2, s = slot & 3;
      int p = s ^ ((r >> 1) & 3);
      gl_lds16(Wt + (size_t)(col0 + r) * CIN + kb + p * 8, (char*)Bs + slot * 16);
    }
    __syncthreads();

    bf8_t afr[4];
#pragma unroll
    for (int mi = 0; mi < 4; ++mi) {
      int r = wm * 64 + mi * 16 + l16;
      int s0 = (2 * quad) ^ (r & 7);
      f32x4 a0 = *reinterpret_cast<const f32x4*>(&As[r * 32 + s0 * 4]);
      f32x4 a1 = *reinterpret_cast<const f32x4*>(&As[r * 32 + (s0 ^ 1) * 4]);
      afr[mi] = bf8_t{ f2b(a0[0]), f2b(a0[1]), f2b(a0[2]), f2b(a0[3]),
                       f2b(a1[0]), f2b(a1[1]), f2b(a1[2]), f2b(a1[3]) };
    }
#pragma unroll
    for (int ni = 0; ni < 4; ++ni) {
      int c = wn * 64 + ni * 16 + l16;
      int sB = quad ^ ((c >> 1) & 3);
      bf8_t bfr = *reinterpret_cast<const bf8_t*>(&Bs[c * 32 + sB * 8]);
#pragma unroll
      for (int mi = 0; mi < 4; ++mi)
        acc[mi][ni] = MFMA16(afr[mi], bfr, acc[mi][ni]);
    }
  }
#pragma unroll
  for (int mi = 0; mi < 4; ++mi)
#pragma unroll
    for (int ni = 0; ni < 4; ++ni)
#pragma unroll
      for (int rr = 0; rr < 4; ++rr) {
        int row = row0 + wm * 64 + mi * 16 + quad * 4 + rr;
        int col = col0 + wn * 64 + ni * 16 + l16;
        Y[(size_t)row * CQKV + col] = __float2bfloat16(acc[mi][ni][rr]);
      }
  // fused per-channel stats: wave covers 64 rows of each of its 64 cols
#pragma unroll
  for (int ni = 0; ni < 4; ++ni) {
    float sp = 0.f, qp = 0.f;
#pragma unroll
    for (int mi = 0; mi < 4; ++mi)
#pragma unroll
      for (int rr = 0; rr < 4; ++rr) {
        float v = acc[mi][ni][rr];
        sp += v; qp += v * v;
      }
    sp += __shfl_xor(sp, 16); sp += __shfl_xor(sp, 32);
    qp += __shfl_xor(qp, 16); qp += __shfl_xor(qp, 32);
    if (quad == 0) {
      int c = col0 + wn * 64 + ni * 16 + l16;
      atomicAdd(&st[c], sp);
      atomicAdd(&st[CQKV + c], qp);
    }
  }
}

// ------------------- out GEMM (fp32 out) + fused stats ---------------------
__global__ __launch_bounds__(256) void k_gemm_o(
    const bf16* __restrict__ AO, const bf16* __restrict__ Wto,
    float* __restrict__ Yo, float* __restrict__ st)
{
  __shared__ __align__(16) bf16 As[128 * 32];
  __shared__ __align__(16) bf16 Bs[128 * 32];
  int tid = threadIdx.x;
  int lane = tid & 63;
  int wave = tid >> 6;
  int quad = lane >> 4, l16 = lane & 15;
  int wm = wave & 1, wn = wave >> 1;
  int row0 = blockIdx.x * 128;

  f32x4 acc[4][4] = {};

  for (int kb = 0; kb < 128; kb += 32) {
    __syncthreads();
#pragma unroll
    for (int j = 0; j < 2; ++j) {
      int slot = tid + 256 * j;
      int r = slot >> 2, s = slot & 3;
      int p = s ^ ((r >> 1) & 3);
      gl_lds16(AO + (size_t)(row0 + r) * 128 + kb + p * 8, (char*)As + slot * 16);
    }
#pragma unroll
    for (int j = 0; j < 2; ++j) {
      int slot = tid + 256 * j;
      int r = slot >> 2, s = slot & 3;
      int p = s ^ ((r >> 1) & 3);
      gl_lds16(Wto + (size_t)r * 128 + kb + p * 8, (char*)Bs + slot * 16);
    }
    __syncthreads();

    bf8_t afr[4];
#pragma unroll
    for (int mi = 0; mi < 4; ++mi) {
      int r = wm * 64 + mi * 16 + l16;
      int sA = quad ^ ((r >> 1) & 3);
      afr[mi] = *reinterpret_cast<const bf8_t*>(&As[r * 32 + sA * 8]);
    }
#pragma unroll
    for (int ni = 0; ni < 4; ++ni) {
      int c = wn * 64 + ni * 16 + l16;
      int sB = quad ^ ((c >> 1) & 3);
      bf8_t bfr = *reinterpret_cast<const bf8_t*>(&Bs[c * 32 + sB * 8]);
#pragma unroll
      for (int mi = 0; mi < 4; ++mi)
        acc[mi][ni] = MFMA16(afr[mi], bfr, acc[mi][ni]);
    }
  }
#pragma unroll
  for (int mi = 0; mi < 4; ++mi)
#pragma unroll
    for (int ni = 0; ni < 4; ++ni)
#pragma unroll
      for (int rr = 0; rr < 4; ++rr) {
        int row = row0 + wm * 64 + mi * 16 + quad * 4 + rr;
        int col = wn * 64 + ni * 16 + l16;
        Yo[(size_t)row * 128 + col] = acc[mi][ni][rr];
      }
#pragma unroll
  for (int ni = 0; ni < 4; ++ni) {
    float sp = 0.f, qp = 0.f;
#pragma unroll
    for (int mi = 0; mi < 4; ++mi)
#pragma unroll
      for (int rr = 0; rr < 4; ++rr) {
        float v = acc[mi][ni][rr];
        sp += v; qp += v * v;
      }
    sp += __shfl_xor(sp, 16); sp += __shfl_xor(sp, 32);
    qp += __shfl_xor(qp, 16); qp += __shfl_xor(qp, 32);
    if (quad == 0) {
      int c = wn * 64 + ni * 16 + l16;
      atomicAdd(&st[c], sp);
      atomicAdd(&st[128 + c], qp);
    }
  }
}

// ------------------- BN scale/shift for the 384 qkv channels ---------------
// q channels (c<128) additionally fold 0.5*log2(e): attention score scale
// 1/sqrt(d)=0.5 and e->2 exponent base (relu commutes with positive scale).
__global__ void k_scales_qkv(const float* __restrict__ st,
                             const float* __restrict__ gq, const float* __restrict__ beq,
                             const float* __restrict__ gk, const float* __restrict__ bek,
                             const float* __restrict__ gv, const float* __restrict__ bev,
                             float* __restrict__ scv, float* __restrict__ shv)
{
  int c = threadIdx.x;
  const float inv = 1.0f / (float)RR;
  float mu  = st[c] * inv;
  float var = st[CQKV + c] * inv - mu * mu;
  const float *g, *be; int cl = c;
  if (c < 128)      { g = gq; be = beq; }
  else if (c < 256) { g = gk; be = bek; cl = c - 128; }
  else              { g = gv; be = bev; cl = c - 256; }
  float sc = g[cl] * rsqrtf(var + EPSB);
  float sh = be[cl] - mu * sc;
  if (c < 128) { sc *= 0.7213475204444817f; sh *= 0.7213475204444817f; }
  scv[c] = sc;
  shv[c] = sh;
}

// ------------------- norm+ReLU: K rows + V (chunk-major A-layout) ----------
// grid (384, 8). Kh: [bh][n][kk] row-major.
// Vt[bh][cidx(16)][dim(32)][quad(4)][j(8)] : element =
//   V[key = cidx*32 + (j>>2)*16 + quad*4 + (j&3)][dim]
// -> chunk-major so each PV A-fragment read in k_attn is one coalesced 1 KB
//    wave access; k-slot permutation matches P's natural register order.
__global__ __launch_bounds__(256) void k_norm_kv(
    const bf16* __restrict__ Y, const float* __restrict__ scv,
    const float* __restrict__ shv, bf16* __restrict__ Kh, bf16* __restrict__ Vt)
{
  __shared__ short vs[64][40];
  int t = threadIdx.x;
  int bh = blockIdx.x, nc = blockIdx.y;
  int bt = bh >> 2, h = bh & 3;
  int n0 = nc * 64;
  int r = t >> 2, cg = t & 3;
  // ---- K phase
  {
    int c = 128 + h * 32 + cg * 8;
    bf8_t y8 = *reinterpret_cast<const bf8_t*>(
        Y + ((size_t)bt * NN + n0 + r) * CQKV + c);
    bf8_t o8;
#pragma unroll
    for (int i = 0; i < 8; ++i)
      o8[i] = f2b(fmaxf(0.f, fmaf(b2f(y8[i]), scv[c + i], shv[c + i])));
    *reinterpret_cast<bf8_t*>(Kh + ((size_t)bh * NN + n0 + r) * 32 + cg * 8) = o8;
  }
  // ---- V phase (LDS transpose into permuted chunk-major A-layout)
  {
    int c = 256 + h * 32 + cg * 8;
    bf8_t y8 = *reinterpret_cast<const bf8_t*>(
        Y + ((size_t)bt * NN + n0 + r) * CQKV + c);
    bf8_t o8;
#pragma unroll
    for (int i = 0; i < 8; ++i)
      o8[i] = f2b(fmaxf(0.f, fmaf(b2f(y8[i]), scv[c + i], shv[c + i])));
    *reinterpret_cast<bf8_t*>(&vs[r][cg * 8]) = o8;
  }
  __syncthreads();
  int dim = t >> 3, kcl = (t >> 2) & 1, quad = t & 3;
  bf8_t w8;
#pragma unroll
  for (int j = 0; j < 8; ++j)
    w8[j] = vs[kcl * 32 + (j >> 2) * 16 + quad * 4 + (j & 3)][dim];
  *reinterpret_cast<bf8_t*>(Vt + (size_t)bh * 16384 +
                            (size_t)(nc * 2 + kcl) * 1024 + dim * 32 + quad * 8) = w8;
}

// ------------------- fused masked attention (swapped operands) -------------
// grid 1536: bh = x % 384 (XCD-local), quarter = x / 384 (8 q-tiles each).
// S^T = MFMA(K, Q): lane owns query l16; per-lane scalar online softmax over
// 8 chunks of 64 keys; P -> PV B-fragment directly (V pre-permuted);
// O^T = MFMA(V^T, P^T); butterfly-redistribute O for a 16B coalesced store.
__global__ __launch_bounds__(256, 4) void k_attn(
    const bf16* __restrict__ Y, const float* __restrict__ scv,
    const float* __restrict__ shv, const bf16* __restrict__ Kh,
    const bf16* __restrict__ Vt, const unsigned int* __restrict__ Amb,
    bf16* __restrict__ AO)
{
  __shared__ __align__(16) bf16 KbS[512 * 32];     // 32 KB, rows 64B swizzled
  int tid = threadIdx.x;
  int wave = tid >> 6, lane = tid & 63;
  int quad = lane >> 4, l16 = lane & 15;
  int bh = blockIdx.x % 384;
  int quarter = blockIdx.x / 384;                  // q-tile quarter (0..3)
  int bt = bh >> 2, h = bh & 3;
  const char* Kp = (const char*)(Kh + (size_t)bh * NN * 32);
  const bf16* Vp = Vt + (size_t)bh * NN * 32;

  // ---- stage K with row-chunk swizzle
#pragma unroll
  for (int i = 0; i < 8; ++i) {
    int t2 = wave * 8 + i;
    int r = t2 * 16 + (lane >> 2);
    int p = (lane & 3) ^ ((r >> 1) & 3);
    gl_lds16(Kp + (size_t)r * 64 + p * 16, (char*)KbS + t2 * 1024 + lane * 16);
  }
  __syncthreads();

  const f32x4 zero = {0.f, 0.f, 0.f, 0.f};
#pragma unroll 1
  for (int it = 0; it < 2; ++it) {
    int nt = quarter * 8 + it * 4 + wave;          // global ntile 0..31
    int n0 = nt * 16;
    // Q inline norm+ReLU from Y: B-fragment (col=query l16, k=dim quad*8+j)
    int cq = h * 32 + quad * 8;
    bf8_t yq = *reinterpret_cast<const bf8_t*>(
        Y + ((size_t)bt * NN + n0 + l16) * CQKV + cq);
    bf8_t qf;
#pragma unroll
    for (int j = 0; j < 8; ++j)
      qf[j] = f2b(fmaxf(0.f, fmaf(b2f(yq[j]), scv[cq + j], shv[cq + j])));
    // mask words: query n0+l16, key-lane quad*4+rr, bit index = key tile
    unsigned int wm[4];
#pragma unroll
    for (int rr = 0; rr < 4; ++rr)
      wm[rr] = Amb[(size_t)(n0 + l16) * 16 + quad * 4 + rr];

    f32x4 o0 = zero, o1 = zero;                    // O^T dims 0-15 / 16-31
    float mrun = 0.f, lrun = 0.f;                  // valid: scores >= 0

#pragma unroll
    for (int c = 0; c < 8; ++c) {
      // S^T chunk: 4 tiles x 16 keys; lane = (key quad*4+rr, query l16)
      f32x4 s[4];
#pragma unroll
      for (int mt = 0; mt < 4; ++mt) {
        int r = (c * 4 + mt) * 16 + l16;
        bf8_t kf = *reinterpret_cast<const bf8_t*>(
            (const char*)KbS + (size_t)r * 64 + ((quad ^ ((r >> 1) & 3)) * 16));
        s[mt] = MFMA16(kf, qf, zero);
      }
      // mask + chunk max (scale already folded into qf)
      float lmax = -1e30f;
#pragma unroll
      for (int mt = 0; mt < 4; ++mt)
#pragma unroll
        for (int rr = 0; rr < 4; ++rr) {
          float v = ((wm[rr] >> (c * 4 + mt)) & 1u) ? s[mt][rr] : -1e30f;
          s[mt][rr] = v;
          lmax = fmaxf(lmax, v);
        }
      lmax = fmaxf(lmax, __shfl_xor(lmax, 16));
      lmax = fmaxf(lmax, __shfl_xor(lmax, 32));
      float mnew = fmaxf(mrun, lmax);
      float alpha = fexp2(mrun - mnew);
      mrun = mnew;
      lrun *= alpha;
#pragma unroll
      for (int rr = 0; rr < 4; ++rr) { o0[rr] *= alpha; o1[rr] *= alpha; }
      // exp2 + partial sum + pack into PV B-fragments (vector-element inserts
      // with constant indices ONLY — no address-taken arrays, no scratch)
      bf8_t f0, f1;
      float ls = 0.f;
#pragma unroll
      for (int mt = 0; mt < 2; ++mt)
#pragma unroll
        for (int rr = 0; rr < 4; ++rr) {
          float p = fexp2(s[mt][rr] - mnew);
          ls += p;
          f0[mt * 4 + rr] = f2b(p);
        }
#pragma unroll
      for (int mt = 2; mt < 4; ++mt)
#pragma unroll
        for (int rr = 0; rr < 4; ++rr) {
          float p = fexp2(s[mt][rr] - mnew);
          ls += p;
          f1[(mt - 2) * 4 + rr] = f2b(p);
        }
      lrun += ls;
      // PV: O^T += V^T_chunk . P^T_chunk  (Vt chunk-major: one coalesced 1 KB
      // wave read per fragment; chunks 2c/2c+1 = keys c*64..+31 / +32..+63)
      const bf16* va = Vp + (size_t)c * 2048 + l16 * 32 + quad * 8;
      o0 = MFMA16(*reinterpret_cast<const bf8_t*>(va),        f0, o0);
      o0 = MFMA16(*reinterpret_cast<const bf8_t*>(va + 1024), f1, o0);
      o1 = MFMA16(*reinterpret_cast<const bf8_t*>(va + 512),  f0, o1);
      o1 = MFMA16(*reinterpret_cast<const bf8_t*>(va + 1536), f1, o1);
    }
    // final: per-lane partial sums -> cross-quad total, divide (lane-local)
    lrun += __shfl_xor(lrun, 16);
    lrun += __shfl_xor(lrun, 32);
    float inv = 1.0f / lrun;
    unsigned int w0 = pk2(o0[0] * inv, o0[1] * inv);   // dims q*4+0, +1
    unsigned int w1 = pk2(o0[2] * inv, o0[3] * inv);   // dims q*4+2, +3
    unsigned int w2 = pk2(o1[0] * inv, o1[1] * inv);   // dims 16+q*4+0, +1
    unsigned int w3 = pk2(o1[2] * inv, o1[3] * inv);
    // butterfly: lane(quad,l16) gathers dims quad*8..+7 of its query l16
    int sL0 = (quad & 1) * 32 + l16;
    int sL1 = sL0 + 16;
    bool hi = quad >= 2;
    unsigned int a0 = __shfl(w0, sL0), b0 = __shfl(w2, sL0);
    unsigned int a1 = __shfl(w1, sL0), b1 = __shfl(w3, sL0);
    unsigned int a2 = __shfl(w0, sL1), b2 = __shfl(w2, sL1);
    unsigned int a3 = __shfl(w1, sL1), b3 = __shfl(w3, sL1);
    u32x4 ov = { hi ? b0 : a0, hi ? b1 : a1, hi ? b2 : a2, hi ? b3 : a3 };
    *reinterpret_cast<u32x4*>(
        AO + ((size_t)bt * NN + n0 + l16) * DD + h * 32 + quad * 8) = ov;
  }
}

// ------------------- final BN + ReLU ---------------------------------------
__global__ __launch_bounds__(256) void k_norm_o(
    const float* __restrict__ Yo, const float* __restrict__ st,
    const float* __restrict__ g, const float* __restrict__ be,
    float* __restrict__ out)
{
  int idx = blockIdx.x * 256 + threadIdx.x;      // < RR*128
  int c = idx & 127;
  const float inv = 1.0f / (float)RR;
  float mu  = st[c] * inv;
  float var = st[128 + c] * inv - mu * mu;
  float sc = g[c] * rsqrtf(var + EPSB);
  float sh = be[c] - mu * sc;
  out[idx] = fmaxf(0.f, fmaf(Yo[idx], sc, sh));
}

// ---------------------------------------------------------------------------
extern "C" void kernel_launch(void* const* d_in, const int* in_sizes, int n_in,
                              void* d_out, int out_size, void* d_ws, size_t ws_size,
                              hipStream_t stream)
{
  const float* X    = (const float*)d_in[0];
  const float* STE  = (const float*)d_in[1];
  const float* Am   = (const float*)d_in[2];
  const float* Wq   = (const float*)d_in[3];
  const float* gq   = (const float*)d_in[5];
  const float* beq  = (const float*)d_in[6];
  const float* Wk   = (const float*)d_in[7];
  const float* gk   = (const float*)d_in[9];
  const float* bek  = (const float*)d_in[10];
  const float* Wv   = (const float*)d_in[11];
  const float* gv   = (const float*)d_in[13];
  const float* bev  = (const float*)d_in[14];
  const float* Wo   = (const float*)d_in[15];
  const float* go   = (const float*)d_in[17];
  const float* beo  = (const float*)d_in[18];
  // biases d_in[4,8,12,16] unused: BN subtracts batch mean -> bias cancels.

  char* ws = (char*)d_ws;
  bf16*  Yqkv = (bf16*)(ws + 0);            // 37,748,736
  float* Yo   = (float*)(ws + 0);           // aliases Yqkv (dead after attn)
  bf16*  Kh   = (bf16*)(ws + 50331648);
  bf16*  Vt   = (bf16*)(ws + 62914560);
  bf16*  AO   = (bf16*)(ws + 75497472);
  bf16*  Wtq  = (bf16*)(ws + 88080384);     // 196,608
  bf16*  Wto  = (bf16*)(ws + 88276992);     // 32,768
  unsigned int* Amb = (unsigned int*)(ws + 88309760);  // 32,768
  float* st   = (float*)(ws + 88342528);    // [0,768) qkv | [768,1024) o
  float* stq  = st;
  float* sto  = st + 768;
  float* scv  = st + 1024;
  float* shv  = st + 1408;

  k_prep<<<484, 256, 0, stream>>>(Wq, Wk, Wv, Wo, Am, Wtq, Wto, Amb, st);
  k_gemm_qkv<<<dim3(RR / 128, 3), 256, 0, stream>>>(X, STE, Wtq, Yqkv, stq);
  k_scales_qkv<<<1, CQKV, 0, stream>>>(stq, gq, beq, gk, bek, gv, bev, scv, shv);
  k_norm_kv<<<dim3(CQKV, 8), 256, 0, stream>>>(Yqkv, scv, shv, Kh, Vt);
  k_attn<<<1536, 256, 0, stream>>>(Yqkv, scv, shv, Kh, Vt, Amb, AO);
  k_gemm_o<<<dim3(RR / 128, 1), 256, 0, stream>>>(AO, Wto, Yo, sto);
  k_norm_o<<<(RR * 128) / 256, 256, 0, stream>>>(Yo, sto, go, beo, (float*)d_out);
}

// Round 3
// 286.545 us; speedup vs baseline: 1.6550x; 1.6433x over previous
//
#include <hip/hip_runtime.h>
#include <hip/hip_bf16.h>

// ---------------------------------------------------------------------------
// SpatialAttention — ROUND 12 (= R11 with the REAL spill cause removed).
//  * R10/R11 regression root-cause (corrected): __launch_bounds__(256,4) on
//    k_attn made the allocator cap at 64 VGPRs (8-waves/EU boundary) and
//    spill ~900 B/thread of live softmax state to scratch -> 352 MB write +
//    356 MB read per dispatch. The p[8] arrays were innocent. Fix: plain
//    __launch_bounds__(256) like R9's k_attn (168 VGPR, zero spill).
//  * Algorithm unchanged from R11: S^T = MFMA(K,Q) lane-owns-query online
//    softmax (base-2 exp, 0.5*log2e folded into q-channel BN), V chunk-major
//    so PV A-fragments are coalesced 1 KB wave reads, P packs straight into
//    the PV B-fragment, butterfly O redistribution, grid 1536, LDS 32 KB.
// Sizes: BT=96, N=512, D=128, heads=4, hd=32, RR=49152. Biases cancel in BN.
// ---------------------------------------------------------------------------

#define BT   96
#define NN   512
#define DD   128
#define CIN  256
#define CQKV 384
#define RR   49152
#define EPSB 1e-5f

using bf16  = __hip_bfloat16;
using bf8_t = __attribute__((ext_vector_type(8))) short;   // 8 x bf16
using f32x4 = __attribute__((ext_vector_type(4))) float;
using u32x4 = __attribute__((ext_vector_type(4))) unsigned int;

#define MFMA16(a,b,c) __builtin_amdgcn_mfma_f32_16x16x32_bf16((a),(b),(c),0,0,0)

__device__ __forceinline__ short f2b(float f) {
  bf16 h = __float2bfloat16(f);
  return *reinterpret_cast<short*>(&h);
}
__device__ __forceinline__ float b2f(short s) {
  bf16 h; *reinterpret_cast<short*>(&h) = s;
  return __bfloat162float(h);
}
__device__ __forceinline__ float fexp2(float x) {
#if __has_builtin(__builtin_amdgcn_exp2f)
  return __builtin_amdgcn_exp2f(x);
#else
  return exp2f(x);
#endif
}
__device__ __forceinline__ unsigned int pk2(float lo, float hi) {
  return (unsigned int)(unsigned short)f2b(lo) |
         ((unsigned int)(unsigned short)f2b(hi) << 16);
}
__device__ __forceinline__ void gl_lds16(const void* g, void* l) {
  __builtin_amdgcn_global_load_lds(
      (const __attribute__((address_space(1))) unsigned int*)g,
      (__attribute__((address_space(3))) unsigned int*)l, 16, 0, 0);
}

// ------------------- prep: W transpose + mask bitmask + zero stats ---------
// Work items: 98304 (Wtq) + 16384 (Wto) + 8192 (Amb) + 1024 (st) = 123904
// -> grid 484 x 256.
__global__ __launch_bounds__(256) void k_prep(
    const float* __restrict__ Wq, const float* __restrict__ Wk,
    const float* __restrict__ Wv, const float* __restrict__ Wo,
    const float* __restrict__ Am,
    bf16* __restrict__ Wtq, bf16* __restrict__ Wto,
    unsigned int* __restrict__ Amb, float* __restrict__ st)
{
  int idx = blockIdx.x * 256 + threadIdx.x;
  if (idx < CQKV * CIN) {                          // Wtq[c][k] = W[k][c]
    int c = idx >> 8;
    int k = idx & 255;
    const float* W = (c < 128) ? Wq : ((c < 256) ? Wk : Wv);
    int cl = c & 127;
    Wtq[idx] = __float2bfloat16(W[(size_t)k * 128 + cl]);
  } else if (idx < CQKV * CIN + 128 * 128) {       // Wto[c][k] = Wo[k][c]
    int j = idx - CQKV * CIN;
    int c = j >> 7, k = j & 127;
    Wto[j] = __float2bfloat16(Wo[(size_t)k * 128 + c]);
  } else if (idx < CQKV * CIN + 128 * 128 + 8192) {  // Amb[n][l16] bit mt
    int j = idx - (CQKV * CIN + 128 * 128);
    int l16 = j & 15, n = j >> 4;
    unsigned int w = 0;
#pragma unroll
    for (int mt = 0; mt < 32; ++mt)
      if (Am[(size_t)n * NN + mt * 16 + l16] > 0.f) w |= (1u << mt);
    Amb[j] = w;
  } else if (idx < CQKV * CIN + 128 * 128 + 8192 + 1024) {
    st[idx - (CQKV * CIN + 128 * 128 + 8192)] = 0.f;
  }
}

// ------------------- QKV GEMM + fused stats --------------------------------
// grid (384,3); 128x128 tile, BK=32; A fp32 via global_load_lds (swizzled).
__global__ __launch_bounds__(256) void k_gemm_qkv(
    const float* __restrict__ X, const float* __restrict__ STE,
    const bf16* __restrict__ Wt, bf16* __restrict__ Y, float* __restrict__ st)
{
  __shared__ __align__(16) float As[128 * 32];
  __shared__ __align__(16) bf16  Bs[128 * 32];
  int tid = threadIdx.x;
  int lane = tid & 63;
  int wave = tid >> 6;
  int quad = lane >> 4, l16 = lane & 15;
  int wm = wave & 1, wn = wave >> 1;
  int row0 = blockIdx.x * 128;
  int col0 = blockIdx.y * 128;

  f32x4 acc[4][4] = {};

  for (int kb = 0; kb < 256; kb += 32) {
    const float* Abase = (kb < 128) ? (X + (size_t)row0 * 128 + kb)
                                    : (STE + (size_t)row0 * 128 + (kb - 128));
    __syncthreads();
#pragma unroll
    for (int j = 0; j < 4; ++j) {
      int slot = tid + 256 * j;
      int r = slot >> 3, s = slot & 7;
      int p = s ^ (r & 7);
      gl_lds16(Abase + (size_t)r * 128 + p * 4, (char*)As + slot * 16);
    }
#pragma unroll
    for (int j = 0; j < 2; ++j) {
      int slot = tid + 256 * j;
      int r = slot >> 2, s = slot & 3;
      int p = s ^ ((r >> 1) & 3);
      gl_lds16(Wt + (size_t)(col0 + r) * CIN + kb + p * 8, (char*)Bs + slot * 16);
    }
    __syncthreads();

    bf8_t afr[4];
#pragma unroll
    for (int mi = 0; mi < 4; ++mi) {
      int r = wm * 64 + mi * 16 + l16;
      int s0 = (2 * quad) ^ (r & 7);
      f32x4 a0 = *reinterpret_cast<const f32x4*>(&As[r * 32 + s0 * 4]);
      f32x4 a1 = *reinterpret_cast<const f32x4*>(&As[r * 32 + (s0 ^ 1) * 4]);
      afr[mi] = bf8_t{ f2b(a0[0]), f2b(a0[1]), f2b(a0[2]), f2b(a0[3]),
                       f2b(a1[0]), f2b(a1[1]), f2b(a1[2]), f2b(a1[3]) };
    }
#pragma unroll
    for (int ni = 0; ni < 4; ++ni) {
      int c = wn * 64 + ni * 16 + l16;
      int sB = quad ^ ((c >> 1) & 3);
      bf8_t bfr = *reinterpret_cast<const bf8_t*>(&Bs[c * 32 + sB * 8]);
#pragma unroll
      for (int mi = 0; mi < 4; ++mi)
        acc[mi][ni] = MFMA16(afr[mi], bfr, acc[mi][ni]);
    }
  }
#pragma unroll
  for (int mi = 0; mi < 4; ++mi)
#pragma unroll
    for (int ni = 0; ni < 4; ++ni)
#pragma unroll
      for (int rr = 0; rr < 4; ++rr) {
        int row = row0 + wm * 64 + mi * 16 + quad * 4 + rr;
        int col = col0 + wn * 64 + ni * 16 + l16;
        Y[(size_t)row * CQKV + col] = __float2bfloat16(acc[mi][ni][rr]);
      }
  // fused per-channel stats: wave covers 64 rows of each of its 64 cols
#pragma unroll
  for (int ni = 0; ni < 4; ++ni) {
    float sp = 0.f, qp = 0.f;
#pragma unroll
    for (int mi = 0; mi < 4; ++mi)
#pragma unroll
      for (int rr = 0; rr < 4; ++rr) {
        float v = acc[mi][ni][rr];
        sp += v; qp += v * v;
      }
    sp += __shfl_xor(sp, 16); sp += __shfl_xor(sp, 32);
    qp += __shfl_xor(qp, 16); qp += __shfl_xor(qp, 32);
    if (quad == 0) {
      int c = col0 + wn * 64 + ni * 16 + l16;
      atomicAdd(&st[c], sp);
      atomicAdd(&st[CQKV + c], qp);
    }
  }
}

// ------------------- out GEMM (fp32 out) + fused stats ---------------------
__global__ __launch_bounds__(256) void k_gemm_o(
    const bf16* __restrict__ AO, const bf16* __restrict__ Wto,
    float* __restrict__ Yo, float* __restrict__ st)
{
  __shared__ __align__(16) bf16 As[128 * 32];
  __shared__ __align__(16) bf16 Bs[128 * 32];
  int tid = threadIdx.x;
  int lane = tid & 63;
  int wave = tid >> 6;
  int quad = lane >> 4, l16 = lane & 15;
  int wm = wave & 1, wn = wave >> 1;
  int row0 = blockIdx.x * 128;

  f32x4 acc[4][4] = {};

  for (int kb = 0; kb < 128; kb += 32) {
    __syncthreads();
#pragma unroll
    for (int j = 0; j < 2; ++j) {
      int slot = tid + 256 * j;
      int r = slot >> 2, s = slot & 3;
      int p = s ^ ((r >> 1) & 3);
      gl_lds16(AO + (size_t)(row0 + r) * 128 + kb + p * 8, (char*)As + slot * 16);
    }
#pragma unroll
    for (int j = 0; j < 2; ++j) {
      int slot = tid + 256 * j;
      int r = slot >> 2, s = slot & 3;
      int p = s ^ ((r >> 1) & 3);
      gl_lds16(Wto + (size_t)r * 128 + kb + p * 8, (char*)Bs + slot * 16);
    }
    __syncthreads();

    bf8_t afr[4];
#pragma unroll
    for (int mi = 0; mi < 4; ++mi) {
      int r = wm * 64 + mi * 16 + l16;
      int sA = quad ^ ((r >> 1) & 3);
      afr[mi] = *reinterpret_cast<const bf8_t*>(&As[r * 32 + sA * 8]);
    }
#pragma unroll
    for (int ni = 0; ni < 4; ++ni) {
      int c = wn * 64 + ni * 16 + l16;
      int sB = quad ^ ((c >> 1) & 3);
      bf8_t bfr = *reinterpret_cast<const bf8_t*>(&Bs[c * 32 + sB * 8]);
#pragma unroll
      for (int mi = 0; mi < 4; ++mi)
        acc[mi][ni] = MFMA16(afr[mi], bfr, acc[mi][ni]);
    }
  }
#pragma unroll
  for (int mi = 0; mi < 4; ++mi)
#pragma unroll
    for (int ni = 0; ni < 4; ++ni)
#pragma unroll
      for (int rr = 0; rr < 4; ++rr) {
        int row = row0 + wm * 64 + mi * 16 + quad * 4 + rr;
        int col = wn * 64 + ni * 16 + l16;
        Yo[(size_t)row * 128 + col] = acc[mi][ni][rr];
      }
#pragma unroll
  for (int ni = 0; ni < 4; ++ni) {
    float sp = 0.f, qp = 0.f;
#pragma unroll
    for (int mi = 0; mi < 4; ++mi)
#pragma unroll
      for (int rr = 0; rr < 4; ++rr) {
        float v = acc[mi][ni][rr];
        sp += v; qp += v * v;
      }
    sp += __shfl_xor(sp, 16); sp += __shfl_xor(sp, 32);
    qp += __shfl_xor(qp, 16); qp += __shfl_xor(qp, 32);
    if (quad == 0) {
      int c = wn * 64 + ni * 16 + l16;
      atomicAdd(&st[c], sp);
      atomicAdd(&st[128 + c], qp);
    }
  }
}

// ------------------- BN scale/shift for the 384 qkv channels ---------------
// q channels (c<128) additionally fold 0.5*log2(e): attention score scale
// 1/sqrt(d)=0.5 and e->2 exponent base (relu commutes with positive scale).
__global__ void k_scales_qkv(const float* __restrict__ st,
                             const float* __restrict__ gq, const float* __restrict__ beq,
                             const float* __restrict__ gk, const float* __restrict__ bek,
                             const float* __restrict__ gv, const float* __restrict__ bev,
                             float* __restrict__ scv, float* __restrict__ shv)
{
  int c = threadIdx.x;
  const float inv = 1.0f / (float)RR;
  float mu  = st[c] * inv;
  float var = st[CQKV + c] * inv - mu * mu;
  const float *g, *be; int cl = c;
  if (c < 128)      { g = gq; be = beq; }
  else if (c < 256) { g = gk; be = bek; cl = c - 128; }
  else              { g = gv; be = bev; cl = c - 256; }
  float sc = g[cl] * rsqrtf(var + EPSB);
  float sh = be[cl] - mu * sc;
  if (c < 128) { sc *= 0.7213475204444817f; sh *= 0.7213475204444817f; }
  scv[c] = sc;
  shv[c] = sh;
}

// ------------------- norm+ReLU: K rows + V (chunk-major A-layout) ----------
// grid (384, 8). Kh: [bh][n][kk] row-major.
// Vt[bh][cidx(16)][dim(32)][quad(4)][j(8)] : element =
//   V[key = cidx*32 + (j>>2)*16 + quad*4 + (j&3)][dim]
// -> chunk-major so each PV A-fragment read in k_attn is one coalesced 1 KB
//    wave access; k-slot permutation matches P's natural register order.
__global__ __launch_bounds__(256) void k_norm_kv(
    const bf16* __restrict__ Y, const float* __restrict__ scv,
    const float* __restrict__ shv, bf16* __restrict__ Kh, bf16* __restrict__ Vt)
{
  __shared__ short vs[64][40];
  int t = threadIdx.x;
  int bh = blockIdx.x, nc = blockIdx.y;
  int bt = bh >> 2, h = bh & 3;
  int n0 = nc * 64;
  int r = t >> 2, cg = t & 3;
  // ---- K phase
  {
    int c = 128 + h * 32 + cg * 8;
    bf8_t y8 = *reinterpret_cast<const bf8_t*>(
        Y + ((size_t)bt * NN + n0 + r) * CQKV + c);
    bf8_t o8;
#pragma unroll
    for (int i = 0; i < 8; ++i)
      o8[i] = f2b(fmaxf(0.f, fmaf(b2f(y8[i]), scv[c + i], shv[c + i])));
    *reinterpret_cast<bf8_t*>(Kh + ((size_t)bh * NN + n0 + r) * 32 + cg * 8) = o8;
  }
  // ---- V phase (LDS transpose into permuted chunk-major A-layout)
  {
    int c = 256 + h * 32 + cg * 8;
    bf8_t y8 = *reinterpret_cast<const bf8_t*>(
        Y + ((size_t)bt * NN + n0 + r) * CQKV + c);
    bf8_t o8;
#pragma unroll
    for (int i = 0; i < 8; ++i)
      o8[i] = f2b(fmaxf(0.f, fmaf(b2f(y8[i]), scv[c + i], shv[c + i])));
    *reinterpret_cast<bf8_t*>(&vs[r][cg * 8]) = o8;
  }
  __syncthreads();
  int dim = t >> 3, kcl = (t >> 2) & 1, quad = t & 3;
  bf8_t w8;
#pragma unroll
  for (int j = 0; j < 8; ++j)
    w8[j] = vs[kcl * 32 + (j >> 2) * 16 + quad * 4 + (j & 3)][dim];
  *reinterpret_cast<bf8_t*>(Vt + (size_t)bh * 16384 +
                            (size_t)(nc * 2 + kcl) * 1024 + dim * 32 + quad * 8) = w8;
}

// ------------------- fused masked attention (swapped operands) -------------
// grid 1536: bh = x % 384 (XCD-local), quarter = x / 384 (8 q-tiles each).
// S^T = MFMA(K, Q): lane owns query l16; per-lane scalar online softmax over
// 8 chunks of 64 keys; P -> PV B-fragment directly (V pre-permuted);
// O^T = MFMA(V^T, P^T); butterfly-redistribute O for a 16B coalesced store.
// NOTE: plain launch_bounds — (256,4) made the allocator spill (R10/R11).
__global__ __launch_bounds__(256) void k_attn(
    const bf16* __restrict__ Y, const float* __restrict__ scv,
    const float* __restrict__ shv, const bf16* __restrict__ Kh,
    const bf16* __restrict__ Vt, const unsigned int* __restrict__ Amb,
    bf16* __restrict__ AO)
{
  __shared__ __align__(16) bf16 KbS[512 * 32];     // 32 KB, rows 64B swizzled
  int tid = threadIdx.x;
  int wave = tid >> 6, lane = tid & 63;
  int quad = lane >> 4, l16 = lane & 15;
  int bh = blockIdx.x % 384;
  int quarter = blockIdx.x / 384;                  // q-tile quarter (0..3)
  int bt = bh >> 2, h = bh & 3;
  const char* Kp = (const char*)(Kh + (size_t)bh * NN * 32);
  const bf16* Vp = Vt + (size_t)bh * NN * 32;

  // ---- stage K with row-chunk swizzle
#pragma unroll
  for (int i = 0; i < 8; ++i) {
    int t2 = wave * 8 + i;
    int r = t2 * 16 + (lane >> 2);
    int p = (lane & 3) ^ ((r >> 1) & 3);
    gl_lds16(Kp + (size_t)r * 64 + p * 16, (char*)KbS + t2 * 1024 + lane * 16);
  }
  __syncthreads();

  const f32x4 zero = {0.f, 0.f, 0.f, 0.f};
#pragma unroll 1
  for (int it = 0; it < 2; ++it) {
    int nt = quarter * 8 + it * 4 + wave;          // global ntile 0..31
    int n0 = nt * 16;
    // Q inline norm+ReLU from Y: B-fragment (col=query l16, k=dim quad*8+j)
    int cq = h * 32 + quad * 8;
    bf8_t yq = *reinterpret_cast<const bf8_t*>(
        Y + ((size_t)bt * NN + n0 + l16) * CQKV + cq);
    bf8_t qf;
#pragma unroll
    for (int j = 0; j < 8; ++j)
      qf[j] = f2b(fmaxf(0.f, fmaf(b2f(yq[j]), scv[cq + j], shv[cq + j])));
    // mask words: query n0+l16, key-lane quad*4+rr, bit index = key tile
    unsigned int wm[4];
#pragma unroll
    for (int rr = 0; rr < 4; ++rr)
      wm[rr] = Amb[(size_t)(n0 + l16) * 16 + quad * 4 + rr];

    f32x4 o0 = zero, o1 = zero;                    // O^T dims 0-15 / 16-31
    float mrun = 0.f, lrun = 0.f;                  // valid: scores >= 0

#pragma unroll
    for (int c = 0; c < 8; ++c) {
      // S^T chunk: 4 tiles x 16 keys; lane = (key quad*4+rr, query l16)
      f32x4 s[4];
#pragma unroll
      for (int mt = 0; mt < 4; ++mt) {
        int r = (c * 4 + mt) * 16 + l16;
        bf8_t kf = *reinterpret_cast<const bf8_t*>(
            (const char*)KbS + (size_t)r * 64 + ((quad ^ ((r >> 1) & 3)) * 16));
        s[mt] = MFMA16(kf, qf, zero);
      }
      // mask + chunk max (scale already folded into qf)
      float lmax = -1e30f;
#pragma unroll
      for (int mt = 0; mt < 4; ++mt)
#pragma unroll
        for (int rr = 0; rr < 4; ++rr) {
          float v = ((wm[rr] >> (c * 4 + mt)) & 1u) ? s[mt][rr] : -1e30f;
          s[mt][rr] = v;
          lmax = fmaxf(lmax, v);
        }
      lmax = fmaxf(lmax, __shfl_xor(lmax, 16));
      lmax = fmaxf(lmax, __shfl_xor(lmax, 32));
      float mnew = fmaxf(mrun, lmax);
      float alpha = fexp2(mrun - mnew);
      mrun = mnew;
      lrun *= alpha;
#pragma unroll
      for (int rr = 0; rr < 4; ++rr) { o0[rr] *= alpha; o1[rr] *= alpha; }
      // exp2 + partial sum + pack into PV B-fragments (vector-element inserts
      // with constant indices ONLY — no address-taken arrays)
      bf8_t f0, f1;
      float ls = 0.f;
#pragma unroll
      for (int mt = 0; mt < 2; ++mt)
#pragma unroll
        for (int rr = 0; rr < 4; ++rr) {
          float p = fexp2(s[mt][rr] - mnew);
          ls += p;
          f0[mt * 4 + rr] = f2b(p);
        }
#pragma unroll
      for (int mt = 2; mt < 4; ++mt)
#pragma unroll
        for (int rr = 0; rr < 4; ++rr) {
          float p = fexp2(s[mt][rr] - mnew);
          ls += p;
          f1[(mt - 2) * 4 + rr] = f2b(p);
        }
      lrun += ls;
      // PV: O^T += V^T_chunk . P^T_chunk  (Vt chunk-major: one coalesced 1 KB
      // wave read per fragment; chunks 2c/2c+1 = keys c*64..+31 / +32..+63)
      const bf16* va = Vp + (size_t)c * 2048 + l16 * 32 + quad * 8;
      o0 = MFMA16(*reinterpret_cast<const bf8_t*>(va),        f0, o0);
      o0 = MFMA16(*reinterpret_cast<const bf8_t*>(va + 1024), f1, o0);
      o1 = MFMA16(*reinterpret_cast<const bf8_t*>(va + 512),  f0, o1);
      o1 = MFMA16(*reinterpret_cast<const bf8_t*>(va + 1536), f1, o1);
    }
    // final: per-lane partial sums -> cross-quad total, divide (lane-local)
    lrun += __shfl_xor(lrun, 16);
    lrun += __shfl_xor(lrun, 32);
    float inv = 1.0f / lrun;
    unsigned int w0 = pk2(o0[0] * inv, o0[1] * inv);   // dims q*4+0, +1
    unsigned int w1 = pk2(o0[2] * inv, o0[3] * inv);   // dims q*4+2, +3
    unsigned int w2 = pk2(o1[0] * inv, o1[1] * inv);   // dims 16+q*4+0, +1
    unsigned int w3 = pk2(o1[2] * inv, o1[3] * inv);
    // butterfly: lane(quad,l16) gathers dims quad*8..+7 of its query l16
    int sL0 = (quad & 1) * 32 + l16;
    int sL1 = sL0 + 16;
    bool hi = quad >= 2;
    unsigned int a0 = __shfl(w0, sL0), b0 = __shfl(w2, sL0);
    unsigned int a1 = __shfl(w1, sL0), b1 = __shfl(w3, sL0);
    unsigned int a2 = __shfl(w0, sL1), b2 = __shfl(w2, sL1);
    unsigned int a3 = __shfl(w1, sL1), b3 = __shfl(w3, sL1);
    u32x4 ov = { hi ? b0 : a0, hi ? b1 : a1, hi ? b2 : a2, hi ? b3 : a3 };
    *reinterpret_cast<u32x4*>(
        AO + ((size_t)bt * NN + n0 + l16) * DD + h * 32 + quad * 8) = ov;
  }
}

// ------------------- final BN + ReLU ---------------------------------------
__global__ __launch_bounds__(256) void k_norm_o(
    const float* __restrict__ Yo, const float* __restrict__ st,
    const float* __restrict__ g, const float* __restrict__ be,
    float* __restrict__ out)
{
  int idx = blockIdx.x * 256 + threadIdx.x;      // < RR*128
  int c = idx & 127;
  const float inv = 1.0f / (float)RR;
  float mu  = st[c] * inv;
  float var = st[128 + c] * inv - mu * mu;
  float sc = g[c] * rsqrtf(var + EPSB);
  float sh = be[c] - mu * sc;
  out[idx] = fmaxf(0.f, fmaf(Yo[idx], sc, sh));
}

// ---------------------------------------------------------------------------
extern "C" void kernel_launch(void* const* d_in, const int* in_sizes, int n_in,
                              void* d_out, int out_size, void* d_ws, size_t ws_size,
                              hipStream_t stream)
{
  const float* X    = (const float*)d_in[0];
  const float* STE  = (const float*)d_in[1];
  const float* Am   = (const float*)d_in[2];
  const float* Wq   = (const float*)d_in[3];
  const float* gq   = (const float*)d_in[5];
  const float* beq  = (const float*)d_in[6];
  const float* Wk   = (const float*)d_in[7];
  const float* gk   = (const float*)d_in[9];
  const float* bek  = (const float*)d_in[10];
  const float* Wv   = (const float*)d_in[11];
  const float* gv   = (const float*)d_in[13];
  const float* bev  = (const float*)d_in[14];
  const float* Wo   = (const float*)d_in[15];
  const float* go   = (const float*)d_in[17];
  const float* beo  = (const float*)d_in[18];
  // biases d_in[4,8,12,16] unused: BN subtracts batch mean -> bias cancels.

  char* ws = (char*)d_ws;
  bf16*  Yqkv = (bf16*)(ws + 0);            // 37,748,736
  float* Yo   = (float*)(ws + 0);           // aliases Yqkv (dead after attn)
  bf16*  Kh   = (bf16*)(ws + 50331648);
  bf16*  Vt   = (bf16*)(ws + 62914560);
  bf16*  AO   = (bf16*)(ws + 75497472);
  bf16*  Wtq  = (bf16*)(ws + 88080384);     // 196,608
  bf16*  Wto  = (bf16*)(ws + 88276992);     // 32,768
  unsigned int* Amb = (unsigned int*)(ws + 88309760);  // 32,768
  float* st   = (float*)(ws + 88342528);    // [0,768) qkv | [768,1024) o
  float* stq  = st;
  float* sto  = st + 768;
  float* scv  = st + 1024;
  float* shv  = st + 1408;

  k_prep<<<484, 256, 0, stream>>>(Wq, Wk, Wv, Wo, Am, Wtq, Wto, Amb, st);
  k_gemm_qkv<<<dim3(RR / 128, 3), 256, 0, stream>>>(X, STE, Wtq, Yqkv, stq);
  k_scales_qkv<<<1, CQKV, 0, stream>>>(stq, gq, beq, gk, bek, gv, bev, scv, shv);
  k_norm_kv<<<dim3(CQKV, 8), 256, 0, stream>>>(Yqkv, scv, shv, Kh, Vt);
  k_attn<<<1536, 256, 0, stream>>>(Yqkv, scv, shv, Kh, Vt, Amb, AO);
  k_gemm_o<<<dim3(RR / 128, 1), 256, 0, stream>>>(AO, Wto, Yo, sto);
  k_norm_o<<<(RR * 128) / 256, 256, 0, stream>>>(Yo, sto, go, beo, (float*)d_out);
}

// Round 4
// 278.596 us; speedup vs baseline: 1.7022x; 1.0285x over previous
//
#include <hip/hip_runtime.h>
#include <hip/hip_bf16.h>

// ---------------------------------------------------------------------------
// SpatialAttention — ROUND 13 (= R12 + max-free softmax + bf16-preconverted
// GEMM A operand).
//  * k_attn: scores are >= 0 (ReLU'd Q,K) and the folded base-2 exponent is
//    bounded ~30 (fp32 overflows at 126) -> the online-max machinery is
//    numerically unnecessary. Softmax = exp2(s)/Sigma, masked -> 0 via
//    cndmask. Removes per-chunk fmax tree + 2 serial ds_bpermute shuffles +
//    mrun/alpha rescale AND the cross-chunk scalar dependency, so S-MFMA of
//    chunk c+1 overlaps exp/pack VALU of chunk c.
//  * k_cvt (new): X||STE -> bf16 Xb[49152][256] once (~75 MB traffic);
//    k_gemm_qkv A-path becomes the proven k_gemm_o A-path (no per-k-step
//    f2b repack, A fetch halves, LDS 24->16 KB). Xb aliases Kh/Vt/AO region
//    (dead until k_norm_kv, which runs after the GEMM).
//  * R12 lesson kept: NO second __launch_bounds__ arg on k_attn (it forced a
//    64-VGPR cap and 700 MB of scratch spill in R10/R11).
// Sizes: BT=96, N=512, D=128, heads=4, hd=32, RR=49152. Biases cancel in BN.
// ---------------------------------------------------------------------------

#define BT   96
#define NN   512
#define DD   128
#define CIN  256
#define CQKV 384
#define RR   49152
#define EPSB 1e-5f

using bf16  = __hip_bfloat16;
using bf8_t = __attribute__((ext_vector_type(8))) short;   // 8 x bf16
using f32x4 = __attribute__((ext_vector_type(4))) float;
using u32x4 = __attribute__((ext_vector_type(4))) unsigned int;

#define MFMA16(a,b,c) __builtin_amdgcn_mfma_f32_16x16x32_bf16((a),(b),(c),0,0,0)

__device__ __forceinline__ short f2b(float f) {
  bf16 h = __float2bfloat16(f);
  return *reinterpret_cast<short*>(&h);
}
__device__ __forceinline__ float b2f(short s) {
  bf16 h; *reinterpret_cast<short*>(&h) = s;
  return __bfloat162float(h);
}
__device__ __forceinline__ float fexp2(float x) {
#if __has_builtin(__builtin_amdgcn_exp2f)
  return __builtin_amdgcn_exp2f(x);
#else
  return exp2f(x);
#endif
}
__device__ __forceinline__ unsigned int pk2(float lo, float hi) {
  return (unsigned int)(unsigned short)f2b(lo) |
         ((unsigned int)(unsigned short)f2b(hi) << 16);
}
__device__ __forceinline__ void gl_lds16(const void* g, void* l) {
  __builtin_amdgcn_global_load_lds(
      (const __attribute__((address_space(1))) unsigned int*)g,
      (__attribute__((address_space(3))) unsigned int*)l, 16, 0, 0);
}

// ------------------- prep: W transpose + mask bitmask + zero stats ---------
// Work items: 98304 (Wtq) + 16384 (Wto) + 8192 (Amb) + 1024 (st) = 123904
// -> grid 484 x 256.
__global__ __launch_bounds__(256) void k_prep(
    const float* __restrict__ Wq, const float* __restrict__ Wk,
    const float* __restrict__ Wv, const float* __restrict__ Wo,
    const float* __restrict__ Am,
    bf16* __restrict__ Wtq, bf16* __restrict__ Wto,
    unsigned int* __restrict__ Amb, float* __restrict__ st)
{
  int idx = blockIdx.x * 256 + threadIdx.x;
  if (idx < CQKV * CIN) {                          // Wtq[c][k] = W[k][c]
    int c = idx >> 8;
    int k = idx & 255;
    const float* W = (c < 128) ? Wq : ((c < 256) ? Wk : Wv);
    int cl = c & 127;
    Wtq[idx] = __float2bfloat16(W[(size_t)k * 128 + cl]);
  } else if (idx < CQKV * CIN + 128 * 128) {       // Wto[c][k] = Wo[k][c]
    int j = idx - CQKV * CIN;
    int c = j >> 7, k = j & 127;
    Wto[j] = __float2bfloat16(Wo[(size_t)k * 128 + c]);
  } else if (idx < CQKV * CIN + 128 * 128 + 8192) {  // Amb[n][l16] bit mt
    int j = idx - (CQKV * CIN + 128 * 128);
    int l16 = j & 15, n = j >> 4;
    unsigned int w = 0;
#pragma unroll
    for (int mt = 0; mt < 32; ++mt)
      if (Am[(size_t)n * NN + mt * 16 + l16] > 0.f) w |= (1u << mt);
    Amb[j] = w;
  } else if (idx < CQKV * CIN + 128 * 128 + 8192 + 1024) {
    st[idx - (CQKV * CIN + 128 * 128 + 8192)] = 0.f;
  }
}

// ------------------- X||STE -> bf16 concat ---------------------------------
// Xb[row][256]: cols 0..127 = X[row], 128..255 = STE[row]. grid 6144 x 256.
__global__ __launch_bounds__(256) void k_cvt(
    const float* __restrict__ X, const float* __restrict__ STE,
    bf16* __restrict__ Xb)
{
  int idx = blockIdx.x * 256 + threadIdx.x;        // < 49152*32
  int row = idx >> 5, cg = idx & 31;               // 8 cols per thread
  const float* src = (cg < 16) ? (X + (size_t)row * 128 + cg * 8)
                               : (STE + (size_t)row * 128 + (cg - 16) * 8);
  f32x4 a = *reinterpret_cast<const f32x4*>(src);
  f32x4 b = *reinterpret_cast<const f32x4*>(src + 4);
  bf8_t o = bf8_t{ f2b(a[0]), f2b(a[1]), f2b(a[2]), f2b(a[3]),
                   f2b(b[0]), f2b(b[1]), f2b(b[2]), f2b(b[3]) };
  *reinterpret_cast<bf8_t*>(Xb + (size_t)row * 256 + cg * 8) = o;
}

// ------------------- QKV GEMM + fused stats --------------------------------
// grid (384,3); 128x128 tile, BK=32; A,B both bf16 via global_load_lds.
__global__ __launch_bounds__(256) void k_gemm_qkv(
    const bf16* __restrict__ Xb, const bf16* __restrict__ Wt,
    bf16* __restrict__ Y, float* __restrict__ st)
{
  __shared__ __align__(16) bf16 As[128 * 32];
  __shared__ __align__(16) bf16 Bs[128 * 32];
  int tid = threadIdx.x;
  int lane = tid & 63;
  int wave = tid >> 6;
  int quad = lane >> 4, l16 = lane & 15;
  int wm = wave & 1, wn = wave >> 1;
  int row0 = blockIdx.x * 128;
  int col0 = blockIdx.y * 128;

  f32x4 acc[4][4] = {};

  for (int kb = 0; kb < 256; kb += 32) {
    __syncthreads();
#pragma unroll
    for (int j = 0; j < 2; ++j) {
      int slot = tid + 256 * j;
      int r = slot >> 2, s = slot & 3;
      int p = s ^ ((r >> 1) & 3);
      gl_lds16(Xb + (size_t)(row0 + r) * 256 + kb + p * 8, (char*)As + slot * 16);
    }
#pragma unroll
    for (int j = 0; j < 2; ++j) {
      int slot = tid + 256 * j;
      int r = slot >> 2, s = slot & 3;
      int p = s ^ ((r >> 1) & 3);
      gl_lds16(Wt + (size_t)(col0 + r) * CIN + kb + p * 8, (char*)Bs + slot * 16);
    }
    __syncthreads();

    bf8_t afr[4];
#pragma unroll
    for (int mi = 0; mi < 4; ++mi) {
      int r = wm * 64 + mi * 16 + l16;
      int sA = quad ^ ((r >> 1) & 3);
      afr[mi] = *reinterpret_cast<const bf8_t*>(&As[r * 32 + sA * 8]);
    }
#pragma unroll
    for (int ni = 0; ni < 4; ++ni) {
      int c = wn * 64 + ni * 16 + l16;
      int sB = quad ^ ((c >> 1) & 3);
      bf8_t bfr = *reinterpret_cast<const bf8_t*>(&Bs[c * 32 + sB * 8]);
#pragma unroll
      for (int mi = 0; mi < 4; ++mi)
        acc[mi][ni] = MFMA16(afr[mi], bfr, acc[mi][ni]);
    }
  }
#pragma unroll
  for (int mi = 0; mi < 4; ++mi)
#pragma unroll
    for (int ni = 0; ni < 4; ++ni)
#pragma unroll
      for (int rr = 0; rr < 4; ++rr) {
        int row = row0 + wm * 64 + mi * 16 + quad * 4 + rr;
        int col = col0 + wn * 64 + ni * 16 + l16;
        Y[(size_t)row * CQKV + col] = __float2bfloat16(acc[mi][ni][rr]);
      }
  // fused per-channel stats: wave covers 64 rows of each of its 64 cols
#pragma unroll
  for (int ni = 0; ni < 4; ++ni) {
    float sp = 0.f, qp = 0.f;
#pragma unroll
    for (int mi = 0; mi < 4; ++mi)
#pragma unroll
      for (int rr = 0; rr < 4; ++rr) {
        float v = acc[mi][ni][rr];
        sp += v; qp += v * v;
      }
    sp += __shfl_xor(sp, 16); sp += __shfl_xor(sp, 32);
    qp += __shfl_xor(qp, 16); qp += __shfl_xor(qp, 32);
    if (quad == 0) {
      int c = col0 + wn * 64 + ni * 16 + l16;
      atomicAdd(&st[c], sp);
      atomicAdd(&st[CQKV + c], qp);
    }
  }
}

// ------------------- out GEMM (fp32 out) + fused stats ---------------------
__global__ __launch_bounds__(256) void k_gemm_o(
    const bf16* __restrict__ AO, const bf16* __restrict__ Wto,
    float* __restrict__ Yo, float* __restrict__ st)
{
  __shared__ __align__(16) bf16 As[128 * 32];
  __shared__ __align__(16) bf16 Bs[128 * 32];
  int tid = threadIdx.x;
  int lane = tid & 63;
  int wave = tid >> 6;
  int quad = lane >> 4, l16 = lane & 15;
  int wm = wave & 1, wn = wave >> 1;
  int row0 = blockIdx.x * 128;

  f32x4 acc[4][4] = {};

  for (int kb = 0; kb < 128; kb += 32) {
    __syncthreads();
#pragma unroll
    for (int j = 0; j < 2; ++j) {
      int slot = tid + 256 * j;
      int r = slot >> 2, s = slot & 3;
      int p = s ^ ((r >> 1) & 3);
      gl_lds16(AO + (size_t)(row0 + r) * 128 + kb + p * 8, (char*)As + slot * 16);
    }
#pragma unroll
    for (int j = 0; j < 2; ++j) {
      int slot = tid + 256 * j;
      int r = slot >> 2, s = slot & 3;
      int p = s ^ ((r >> 1) & 3);
      gl_lds16(Wto + (size_t)r * 128 + kb + p * 8, (char*)Bs + slot * 16);
    }
    __syncthreads();

    bf8_t afr[4];
#pragma unroll
    for (int mi = 0; mi < 4; ++mi) {
      int r = wm * 64 + mi * 16 + l16;
      int sA = quad ^ ((r >> 1) & 3);
      afr[mi] = *reinterpret_cast<const bf8_t*>(&As[r * 32 + sA * 8]);
    }
#pragma unroll
    for (int ni = 0; ni < 4; ++ni) {
      int c = wn * 64 + ni * 16 + l16;
      int sB = quad ^ ((c >> 1) & 3);
      bf8_t bfr = *reinterpret_cast<const bf8_t*>(&Bs[c * 32 + sB * 8]);
#pragma unroll
      for (int mi = 0; mi < 4; ++mi)
        acc[mi][ni] = MFMA16(afr[mi], bfr, acc[mi][ni]);
    }
  }
#pragma unroll
  for (int mi = 0; mi < 4; ++mi)
#pragma unroll
    for (int ni = 0; ni < 4; ++ni)
#pragma unroll
      for (int rr = 0; rr < 4; ++rr) {
        int row = row0 + wm * 64 + mi * 16 + quad * 4 + rr;
        int col = wn * 64 + ni * 16 + l16;
        Yo[(size_t)row * 128 + col] = acc[mi][ni][rr];
      }
#pragma unroll
  for (int ni = 0; ni < 4; ++ni) {
    float sp = 0.f, qp = 0.f;
#pragma unroll
    for (int mi = 0; mi < 4; ++mi)
#pragma unroll
      for (int rr = 0; rr < 4; ++rr) {
        float v = acc[mi][ni][rr];
        sp += v; qp += v * v;
      }
    sp += __shfl_xor(sp, 16); sp += __shfl_xor(sp, 32);
    qp += __shfl_xor(qp, 16); qp += __shfl_xor(qp, 32);
    if (quad == 0) {
      int c = wn * 64 + ni * 16 + l16;
      atomicAdd(&st[c], sp);
      atomicAdd(&st[128 + c], qp);
    }
  }
}

// ------------------- BN scale/shift for the 384 qkv channels ---------------
// q channels (c<128) additionally fold 0.5*log2(e): attention score scale
// 1/sqrt(d)=0.5 and e->2 exponent base (relu commutes with positive scale).
__global__ void k_scales_qkv(const float* __restrict__ st,
                             const float* __restrict__ gq, const float* __restrict__ beq,
                             const float* __restrict__ gk, const float* __restrict__ bek,
                             const float* __restrict__ gv, const float* __restrict__ bev,
                             float* __restrict__ scv, float* __restrict__ shv)
{
  int c = threadIdx.x;
  const float inv = 1.0f / (float)RR;
  float mu  = st[c] * inv;
  float var = st[CQKV + c] * inv - mu * mu;
  const float *g, *be; int cl = c;
  if (c < 128)      { g = gq; be = beq; }
  else if (c < 256) { g = gk; be = bek; cl = c - 128; }
  else              { g = gv; be = bev; cl = c - 256; }
  float sc = g[cl] * rsqrtf(var + EPSB);
  float sh = be[cl] - mu * sc;
  if (c < 128) { sc *= 0.7213475204444817f; sh *= 0.7213475204444817f; }
  scv[c] = sc;
  shv[c] = sh;
}

// ------------------- norm+ReLU: K rows + V (chunk-major A-layout) ----------
// grid (384, 8). Kh: [bh][n][kk] row-major.
// Vt[bh][cidx(16)][dim(32)][quad(4)][j(8)] : element =
//   V[key = cidx*32 + (j>>2)*16 + quad*4 + (j&3)][dim]
// -> chunk-major so each PV A-fragment read in k_attn is one coalesced 1 KB
//    wave access; k-slot permutation matches P's natural register order.
__global__ __launch_bounds__(256) void k_norm_kv(
    const bf16* __restrict__ Y, const float* __restrict__ scv,
    const float* __restrict__ shv, bf16* __restrict__ Kh, bf16* __restrict__ Vt)
{
  __shared__ short vs[64][40];
  int t = threadIdx.x;
  int bh = blockIdx.x, nc = blockIdx.y;
  int bt = bh >> 2, h = bh & 3;
  int n0 = nc * 64;
  int r = t >> 2, cg = t & 3;
  // ---- K phase
  {
    int c = 128 + h * 32 + cg * 8;
    bf8_t y8 = *reinterpret_cast<const bf8_t*>(
        Y + ((size_t)bt * NN + n0 + r) * CQKV + c);
    bf8_t o8;
#pragma unroll
    for (int i = 0; i < 8; ++i)
      o8[i] = f2b(fmaxf(0.f, fmaf(b2f(y8[i]), scv[c + i], shv[c + i])));
    *reinterpret_cast<bf8_t*>(Kh + ((size_t)bh * NN + n0 + r) * 32 + cg * 8) = o8;
  }
  // ---- V phase (LDS transpose into permuted chunk-major A-layout)
  {
    int c = 256 + h * 32 + cg * 8;
    bf8_t y8 = *reinterpret_cast<const bf8_t*>(
        Y + ((size_t)bt * NN + n0 + r) * CQKV + c);
    bf8_t o8;
#pragma unroll
    for (int i = 0; i < 8; ++i)
      o8[i] = f2b(fmaxf(0.f, fmaf(b2f(y8[i]), scv[c + i], shv[c + i])));
    *reinterpret_cast<bf8_t*>(&vs[r][cg * 8]) = o8;
  }
  __syncthreads();
  int dim = t >> 3, kcl = (t >> 2) & 1, quad = t & 3;
  bf8_t w8;
#pragma unroll
  for (int j = 0; j < 8; ++j)
    w8[j] = vs[kcl * 32 + (j >> 2) * 16 + quad * 4 + (j & 3)][dim];
  *reinterpret_cast<bf8_t*>(Vt + (size_t)bh * 16384 +
                            (size_t)(nc * 2 + kcl) * 1024 + dim * 32 + quad * 8) = w8;
}

// ------------------- fused masked attention (max-free softmax) -------------
// grid 1536: bh = x % 384 (XCD-local), quarter = x / 384 (8 q-tiles each).
// S^T = MFMA(K, Q): lane owns query l16. Scores >= 0 (ReLU'd Q,K) and the
// folded base-2 exponent is bounded ~30 << 126 -> NO max subtraction needed:
// p = masked ? 0 : exp2(s); l = Sigma p. No per-chunk shuffles, no rescale,
// no cross-chunk scalar dependency -> chunks software-pipeline freely.
// NOTE: plain launch_bounds — (256,4) made the allocator spill (R10/R11).
__global__ __launch_bounds__(256) void k_attn(
    const bf16* __restrict__ Y, const float* __restrict__ scv,
    const float* __restrict__ shv, const bf16* __restrict__ Kh,
    const bf16* __restrict__ Vt, const unsigned int* __restrict__ Amb,
    bf16* __restrict__ AO)
{
  __shared__ __align__(16) bf16 KbS[512 * 32];     // 32 KB, rows 64B swizzled
  int tid = threadIdx.x;
  int wave = tid >> 6, lane = tid & 63;
  int quad = lane >> 4, l16 = lane & 15;
  int bh = blockIdx.x % 384;
  int quarter = blockIdx.x / 384;                  // q-tile quarter (0..3)
  int bt = bh >> 2, h = bh & 3;
  const char* Kp = (const char*)(Kh + (size_t)bh * NN * 32);
  const bf16* Vp = Vt + (size_t)bh * NN * 32;

  // ---- stage K with row-chunk swizzle
#pragma unroll
  for (int i = 0; i < 8; ++i) {
    int t2 = wave * 8 + i;
    int r = t2 * 16 + (lane >> 2);
    int p = (lane & 3) ^ ((r >> 1) & 3);
    gl_lds16(Kp + (size_t)r * 64 + p * 16, (char*)KbS + t2 * 1024 + lane * 16);
  }
  __syncthreads();

  const f32x4 zero = {0.f, 0.f, 0.f, 0.f};
#pragma unroll 1
  for (int it = 0; it < 2; ++it) {
    int nt = quarter * 8 + it * 4 + wave;          // global ntile 0..31
    int n0 = nt * 16;
    // Q inline norm+ReLU from Y: B-fragment (col=query l16, k=dim quad*8+j)
    int cq = h * 32 + quad * 8;
    bf8_t yq = *reinterpret_cast<const bf8_t*>(
        Y + ((size_t)bt * NN + n0 + l16) * CQKV + cq);
    bf8_t qf;
#pragma unroll
    for (int j = 0; j < 8; ++j)
      qf[j] = f2b(fmaxf(0.f, fmaf(b2f(yq[j]), scv[cq + j], shv[cq + j])));
    // mask words: query n0+l16, key-lane quad*4+rr, bit index = key tile
    unsigned int wm[4];
#pragma unroll
    for (int rr = 0; rr < 4; ++rr)
      wm[rr] = Amb[(size_t)(n0 + l16) * 16 + quad * 4 + rr];

    f32x4 o0 = zero, o1 = zero;                    // O^T dims 0-15 / 16-31
    float lrun = 0.f;

#pragma unroll
    for (int c = 0; c < 8; ++c) {
      // S^T chunk: 4 tiles x 16 keys; lane = (key quad*4+rr, query l16)
      f32x4 s[4];
#pragma unroll
      for (int mt = 0; mt < 4; ++mt) {
        int r = (c * 4 + mt) * 16 + l16;
        bf8_t kf = *reinterpret_cast<const bf8_t*>(
            (const char*)KbS + (size_t)r * 64 + ((quad ^ ((r >> 1) & 3)) * 16));
        s[mt] = MFMA16(kf, qf, zero);
      }
      // exp2 + mask->0 + partial sum + pack into PV B-fragments
      bf8_t f0, f1;
#pragma unroll
      for (int mt = 0; mt < 2; ++mt)
#pragma unroll
        for (int rr = 0; rr < 4; ++rr) {
          float p = ((wm[rr] >> (c * 4 + mt)) & 1u) ? fexp2(s[mt][rr]) : 0.f;
          lrun += p;
          f0[mt * 4 + rr] = f2b(p);
        }
#pragma unroll
      for (int mt = 2; mt < 4; ++mt)
#pragma unroll
        for (int rr = 0; rr < 4; ++rr) {
          float p = ((wm[rr] >> (c * 4 + mt)) & 1u) ? fexp2(s[mt][rr]) : 0.f;
          lrun += p;
          f1[(mt - 2) * 4 + rr] = f2b(p);
        }
      // PV: O^T += V^T_chunk . P^T_chunk  (Vt chunk-major: one coalesced 1 KB
      // wave read per fragment; chunks 2c/2c+1 = keys c*64..+31 / +32..+63)
      const bf16* va = Vp + (size_t)c * 2048 + l16 * 32 + quad * 8;
      o0 = MFMA16(*reinterpret_cast<const bf8_t*>(va),        f0, o0);
      o0 = MFMA16(*reinterpret_cast<const bf8_t*>(va + 1024), f1, o0);
      o1 = MFMA16(*reinterpret_cast<const bf8_t*>(va + 512),  f0, o1);
      o1 = MFMA16(*reinterpret_cast<const bf8_t*>(va + 1536), f1, o1);
    }
    // final: per-lane partial sums -> cross-quad total, divide (lane-local)
    lrun += __shfl_xor(lrun, 16);
    lrun += __shfl_xor(lrun, 32);
    float inv = 1.0f / lrun;
    unsigned int w0 = pk2(o0[0] * inv, o0[1] * inv);   // dims q*4+0, +1
    unsigned int w1 = pk2(o0[2] * inv, o0[3] * inv);   // dims q*4+2, +3
    unsigned int w2 = pk2(o1[0] * inv, o1[1] * inv);   // dims 16+q*4+0, +1
    unsigned int w3 = pk2(o1[2] * inv, o1[3] * inv);
    // butterfly: lane(quad,l16) gathers dims quad*8..+7 of its query l16
    int sL0 = (quad & 1) * 32 + l16;
    int sL1 = sL0 + 16;
    bool hi = quad >= 2;
    unsigned int a0 = __shfl(w0, sL0), b0 = __shfl(w2, sL0);
    unsigned int a1 = __shfl(w1, sL0), b1 = __shfl(w3, sL0);
    unsigned int a2 = __shfl(w0, sL1), b2 = __shfl(w2, sL1);
    unsigned int a3 = __shfl(w1, sL1), b3 = __shfl(w3, sL1);
    u32x4 ov = { hi ? b0 : a0, hi ? b1 : a1, hi ? b2 : a2, hi ? b3 : a3 };
    *reinterpret_cast<u32x4*>(
        AO + ((size_t)bt * NN + n0 + l16) * DD + h * 32 + quad * 8) = ov;
  }
}

// ------------------- final BN + ReLU ---------------------------------------
__global__ __launch_bounds__(256) void k_norm_o(
    const float* __restrict__ Yo, const float* __restrict__ st,
    const float* __restrict__ g, const float* __restrict__ be,
    float* __restrict__ out)
{
  int idx = blockIdx.x * 256 + threadIdx.x;      // < RR*128
  int c = idx & 127;
  const float inv = 1.0f / (float)RR;
  float mu  = st[c] * inv;
  float var = st[128 + c] * inv - mu * mu;
  float sc = g[c] * rsqrtf(var + EPSB);
  float sh = be[c] - mu * sc;
  out[idx] = fmaxf(0.f, fmaf(Yo[idx], sc, sh));
}

// ---------------------------------------------------------------------------
extern "C" void kernel_launch(void* const* d_in, const int* in_sizes, int n_in,
                              void* d_out, int out_size, void* d_ws, size_t ws_size,
                              hipStream_t stream)
{
  const float* X    = (const float*)d_in[0];
  const float* STE  = (const float*)d_in[1];
  const float* Am   = (const float*)d_in[2];
  const float* Wq   = (const float*)d_in[3];
  const float* gq   = (const float*)d_in[5];
  const float* beq  = (const float*)d_in[6];
  const float* Wk   = (const float*)d_in[7];
  const float* gk   = (const float*)d_in[9];
  const float* bek  = (const float*)d_in[10];
  const float* Wv   = (const float*)d_in[11];
  const float* gv   = (const float*)d_in[13];
  const float* bev  = (const float*)d_in[14];
  const float* Wo   = (const float*)d_in[15];
  const float* go   = (const float*)d_in[17];
  const float* beo  = (const float*)d_in[18];
  // biases d_in[4,8,12,16] unused: BN subtracts batch mean -> bias cancels.

  char* ws = (char*)d_ws;
  bf16*  Yqkv = (bf16*)(ws + 0);            // 37,748,736
  float* Yo   = (float*)(ws + 0);           // aliases Yqkv (dead after attn)
  bf16*  Xb   = (bf16*)(ws + 50331648);     // 25,165,824 — aliases Kh/Vt:
                                            //   dead before k_norm_kv runs
  bf16*  Kh   = (bf16*)(ws + 50331648);
  bf16*  Vt   = (bf16*)(ws + 62914560);
  bf16*  AO   = (bf16*)(ws + 75497472);
  bf16*  Wtq  = (bf16*)(ws + 88080384);     // 196,608
  bf16*  Wto  = (bf16*)(ws + 88276992);     // 32,768
  unsigned int* Amb = (unsigned int*)(ws + 88309760);  // 32,768
  float* st   = (float*)(ws + 88342528);    // [0,768) qkv | [768,1024) o
  float* stq  = st;
  float* sto  = st + 768;
  float* scv  = st + 1024;
  float* shv  = st + 1408;

  k_prep<<<484, 256, 0, stream>>>(Wq, Wk, Wv, Wo, Am, Wtq, Wto, Amb, st);
  k_cvt<<<6144, 256, 0, stream>>>(X, STE, Xb);
  k_gemm_qkv<<<dim3(RR / 128, 3), 256, 0, stream>>>(Xb, Wtq, Yqkv, stq);
  k_scales_qkv<<<1, CQKV, 0, stream>>>(stq, gq, beq, gk, bek, gv, bev, scv, shv);
  k_norm_kv<<<dim3(CQKV, 8), 256, 0, stream>>>(Yqkv, scv, shv, Kh, Vt);
  k_attn<<<1536, 256, 0, stream>>>(Yqkv, scv, shv, Kh, Vt, Amb, AO);
  k_gemm_o<<<dim3(RR / 128, 1), 256, 0, stream>>>(AO, Wto, Yo, sto);
  k_norm_o<<<(RR * 128) / 256, 256, 0, stream>>>(Yo, sto, go, beo, (float*)d_out);
}

// Round 5
// 270.257 us; speedup vs baseline: 1.7548x; 1.0309x over previous
//
#include <hip/hip_runtime.h>
#include <hip/hip_bf16.h>

// ---------------------------------------------------------------------------
// SpatialAttention — ROUND 14 (= R13 + attn unroll cap + BK=64 GEMMs + merged
// prep/cvt).
//  * k_attn: #pragma unroll 2 on the chunk loop. R13's full unroll hoisted up
//    to 32 V-fragment loads -> 216 VGPR -> 2 waves/SIMD (2 blocks/CU, 3
//    residency rounds at grid 1536). Capping in-flight chunks bounds V state
//    ~32 VGPR; target <=170 VGPR = 3 waves/SIMD. TLP replaces ILP.
//  * k_gemm_qkv / k_gemm_o: BK 32->64 (LDS 16+16 KB). Same bytes staged, half
//    the barrier pairs, 32 MFMAs per phase -> less barrier-drain stall
//    (m233: 2-phase stage+barrier overhead dominates at BK=32).
//  * k_prep absorbs k_cvt (disjoint elementwise ranges; one fewer launch).
//  * R12 lesson kept: NO second __launch_bounds__ arg on k_attn.
// Sizes: BT=96, N=512, D=128, heads=4, hd=32, RR=49152. Biases cancel in BN.
// ---------------------------------------------------------------------------

#define BT   96
#define NN   512
#define DD   128
#define CIN  256
#define CQKV 384
#define RR   49152
#define EPSB 1e-5f

using bf16  = __hip_bfloat16;
using bf8_t = __attribute__((ext_vector_type(8))) short;   // 8 x bf16
using f32x4 = __attribute__((ext_vector_type(4))) float;
using u32x4 = __attribute__((ext_vector_type(4))) unsigned int;

#define MFMA16(a,b,c) __builtin_amdgcn_mfma_f32_16x16x32_bf16((a),(b),(c),0,0,0)

__device__ __forceinline__ short f2b(float f) {
  bf16 h = __float2bfloat16(f);
  return *reinterpret_cast<short*>(&h);
}
__device__ __forceinline__ float b2f(short s) {
  bf16 h; *reinterpret_cast<short*>(&h) = s;
  return __bfloat162float(h);
}
__device__ __forceinline__ float fexp2(float x) {
#if __has_builtin(__builtin_amdgcn_exp2f)
  return __builtin_amdgcn_exp2f(x);
#else
  return exp2f(x);
#endif
}
__device__ __forceinline__ unsigned int pk2(float lo, float hi) {
  return (unsigned int)(unsigned short)f2b(lo) |
         ((unsigned int)(unsigned short)f2b(hi) << 16);
}
__device__ __forceinline__ void gl_lds16(const void* g, void* l) {
  __builtin_amdgcn_global_load_lds(
      (const __attribute__((address_space(1))) unsigned int*)g,
      (__attribute__((address_space(3))) unsigned int*)l, 16, 0, 0);
}

// ------------------- prep: W transpose + mask + zero stats + X||STE cvt ----
// Items: 98304 (Wtq) + 16384 (Wto) + 8192 (Amb) + 1024 (st) = 123904, then
// 49152*32 = 1572864 cvt items. Total 1696768 -> grid 6628 x 256.
__global__ __launch_bounds__(256) void k_prep(
    const float* __restrict__ Wq, const float* __restrict__ Wk,
    const float* __restrict__ Wv, const float* __restrict__ Wo,
    const float* __restrict__ Am, const float* __restrict__ X,
    const float* __restrict__ STE,
    bf16* __restrict__ Wtq, bf16* __restrict__ Wto,
    unsigned int* __restrict__ Amb, float* __restrict__ st,
    bf16* __restrict__ Xb)
{
  int idx = blockIdx.x * 256 + threadIdx.x;
  if (idx < CQKV * CIN) {                          // Wtq[c][k] = W[k][c]
    int c = idx >> 8;
    int k = idx & 255;
    const float* W = (c < 128) ? Wq : ((c < 256) ? Wk : Wv);
    int cl = c & 127;
    Wtq[idx] = __float2bfloat16(W[(size_t)k * 128 + cl]);
  } else if (idx < CQKV * CIN + 128 * 128) {       // Wto[c][k] = Wo[k][c]
    int j = idx - CQKV * CIN;
    int c = j >> 7, k = j & 127;
    Wto[j] = __float2bfloat16(Wo[(size_t)k * 128 + c]);
  } else if (idx < CQKV * CIN + 128 * 128 + 8192) {  // Amb[n][l16] bit mt
    int j = idx - (CQKV * CIN + 128 * 128);
    int l16 = j & 15, n = j >> 4;
    unsigned int w = 0;
#pragma unroll
    for (int mt = 0; mt < 32; ++mt)
      if (Am[(size_t)n * NN + mt * 16 + l16] > 0.f) w |= (1u << mt);
    Amb[j] = w;
  } else if (idx < CQKV * CIN + 128 * 128 + 8192 + 1024) {
    st[idx - (CQKV * CIN + 128 * 128 + 8192)] = 0.f;
  } else {                                         // X||STE -> bf16 Xb
    int j = idx - (CQKV * CIN + 128 * 128 + 8192 + 1024);
    int row = j >> 5, cg = j & 31;                 // 8 cols per thread
    const float* src = (cg < 16) ? (X + (size_t)row * 128 + cg * 8)
                                 : (STE + (size_t)row * 128 + (cg - 16) * 8);
    f32x4 a = *reinterpret_cast<const f32x4*>(src);
    f32x4 b = *reinterpret_cast<const f32x4*>(src + 4);
    bf8_t o = bf8_t{ f2b(a[0]), f2b(a[1]), f2b(a[2]), f2b(a[3]),
                     f2b(b[0]), f2b(b[1]), f2b(b[2]), f2b(b[3]) };
    *reinterpret_cast<bf8_t*>(Xb + (size_t)row * 256 + cg * 8) = o;
  }
}

// ------------------- QKV GEMM + fused stats --------------------------------
// grid (384,3); 128x128 tile, BK=64 (4 k-steps, half the barriers of BK=32).
__global__ __launch_bounds__(256) void k_gemm_qkv(
    const bf16* __restrict__ Xb, const bf16* __restrict__ Wt,
    bf16* __restrict__ Y, float* __restrict__ st)
{
  __shared__ __align__(16) bf16 As[128 * 64];      // 16 KB, rows 128B
  __shared__ __align__(16) bf16 Bs[128 * 64];
  int tid = threadIdx.x;
  int lane = tid & 63;
  int wave = tid >> 6;
  int quad = lane >> 4, l16 = lane & 15;
  int wm = wave & 1, wn = wave >> 1;
  int row0 = blockIdx.x * 128;
  int col0 = blockIdx.y * 128;

  f32x4 acc[4][4] = {};

  for (int kb = 0; kb < 256; kb += 64) {
    __syncthreads();
#pragma unroll
    for (int j = 0; j < 4; ++j) {
      int slot = tid + 256 * j;
      int r = slot >> 3, s = slot & 7;
      int p = s ^ (r & 7);
      gl_lds16(Xb + (size_t)(row0 + r) * 256 + kb + p * 8, (char*)As + slot * 16);
    }
#pragma unroll
    for (int j = 0; j < 4; ++j) {
      int slot = tid + 256 * j;
      int r = slot >> 3, s = slot & 7;
      int p = s ^ (r & 7);
      gl_lds16(Wt + (size_t)(col0 + r) * CIN + kb + p * 8, (char*)Bs + slot * 16);
    }
    __syncthreads();

#pragma unroll
    for (int t = 0; t < 2; ++t) {
      bf8_t afr[4];
#pragma unroll
      for (int mi = 0; mi < 4; ++mi) {
        int r = wm * 64 + mi * 16 + l16;
        int sub = (t * 4 + quad) ^ (r & 7);
        afr[mi] = *reinterpret_cast<const bf8_t*>((char*)As + r * 128 + sub * 16);
      }
#pragma unroll
      for (int ni = 0; ni < 4; ++ni) {
        int c = wn * 64 + ni * 16 + l16;
        int sub = (t * 4 + quad) ^ (c & 7);
        bf8_t bfr = *reinterpret_cast<const bf8_t*>((char*)Bs + c * 128 + sub * 16);
#pragma unroll
        for (int mi = 0; mi < 4; ++mi)
          acc[mi][ni] = MFMA16(afr[mi], bfr, acc[mi][ni]);
      }
    }
  }
#pragma unroll
  for (int mi = 0; mi < 4; ++mi)
#pragma unroll
    for (int ni = 0; ni < 4; ++ni)
#pragma unroll
      for (int rr = 0; rr < 4; ++rr) {
        int row = row0 + wm * 64 + mi * 16 + quad * 4 + rr;
        int col = col0 + wn * 64 + ni * 16 + l16;
        Y[(size_t)row * CQKV + col] = __float2bfloat16(acc[mi][ni][rr]);
      }
  // fused per-channel stats: wave covers 64 rows of each of its 64 cols
#pragma unroll
  for (int ni = 0; ni < 4; ++ni) {
    float sp = 0.f, qp = 0.f;
#pragma unroll
    for (int mi = 0; mi < 4; ++mi)
#pragma unroll
      for (int rr = 0; rr < 4; ++rr) {
        float v = acc[mi][ni][rr];
        sp += v; qp += v * v;
      }
    sp += __shfl_xor(sp, 16); sp += __shfl_xor(sp, 32);
    qp += __shfl_xor(qp, 16); qp += __shfl_xor(qp, 32);
    if (quad == 0) {
      int c = col0 + wn * 64 + ni * 16 + l16;
      atomicAdd(&st[c], sp);
      atomicAdd(&st[CQKV + c], qp);
    }
  }
}

// ------------------- out GEMM (fp32 out) + fused stats, BK=64 --------------
__global__ __launch_bounds__(256) void k_gemm_o(
    const bf16* __restrict__ AO, const bf16* __restrict__ Wto,
    float* __restrict__ Yo, float* __restrict__ st)
{
  __shared__ __align__(16) bf16 As[128 * 64];
  __shared__ __align__(16) bf16 Bs[128 * 64];
  int tid = threadIdx.x;
  int lane = tid & 63;
  int wave = tid >> 6;
  int quad = lane >> 4, l16 = lane & 15;
  int wm = wave & 1, wn = wave >> 1;
  int row0 = blockIdx.x * 128;

  f32x4 acc[4][4] = {};

  for (int kb = 0; kb < 128; kb += 64) {
    __syncthreads();
#pragma unroll
    for (int j = 0; j < 4; ++j) {
      int slot = tid + 256 * j;
      int r = slot >> 3, s = slot & 7;
      int p = s ^ (r & 7);
      gl_lds16(AO + (size_t)(row0 + r) * 128 + kb + p * 8, (char*)As + slot * 16);
    }
#pragma unroll
    for (int j = 0; j < 4; ++j) {
      int slot = tid + 256 * j;
      int r = slot >> 3, s = slot & 7;
      int p = s ^ (r & 7);
      gl_lds16(Wto + (size_t)r * 128 + kb + p * 8, (char*)Bs + slot * 16);
    }
    __syncthreads();

#pragma unroll
    for (int t = 0; t < 2; ++t) {
      bf8_t afr[4];
#pragma unroll
      for (int mi = 0; mi < 4; ++mi) {
        int r = wm * 64 + mi * 16 + l16;
        int sub = (t * 4 + quad) ^ (r & 7);
        afr[mi] = *reinterpret_cast<const bf8_t*>((char*)As + r * 128 + sub * 16);
      }
#pragma unroll
      for (int ni = 0; ni < 4; ++ni) {
        int c = wn * 64 + ni * 16 + l16;
        int sub = (t * 4 + quad) ^ (c & 7);
        bf8_t bfr = *reinterpret_cast<const bf8_t*>((char*)Bs + c * 128 + sub * 16);
#pragma unroll
        for (int mi = 0; mi < 4; ++mi)
          acc[mi][ni] = MFMA16(afr[mi], bfr, acc[mi][ni]);
      }
    }
  }
#pragma unroll
  for (int mi = 0; mi < 4; ++mi)
#pragma unroll
    for (int ni = 0; ni < 4; ++ni)
#pragma unroll
      for (int rr = 0; rr < 4; ++rr) {
        int row = row0 + wm * 64 + mi * 16 + quad * 4 + rr;
        int col = wn * 64 + ni * 16 + l16;
        Yo[(size_t)row * 128 + col] = acc[mi][ni][rr];
      }
#pragma unroll
  for (int ni = 0; ni < 4; ++ni) {
    float sp = 0.f, qp = 0.f;
#pragma unroll
    for (int mi = 0; mi < 4; ++mi)
#pragma unroll
      for (int rr = 0; rr < 4; ++rr) {
        float v = acc[mi][ni][rr];
        sp += v; qp += v * v;
      }
    sp += __shfl_xor(sp, 16); sp += __shfl_xor(sp, 32);
    qp += __shfl_xor(qp, 16); qp += __shfl_xor(qp, 32);
    if (quad == 0) {
      int c = wn * 64 + ni * 16 + l16;
      atomicAdd(&st[c], sp);
      atomicAdd(&st[128 + c], qp);
    }
  }
}

// ------------------- BN scale/shift for the 384 qkv channels ---------------
// q channels (c<128) additionally fold 0.5*log2(e): attention score scale
// 1/sqrt(d)=0.5 and e->2 exponent base (relu commutes with positive scale).
__global__ void k_scales_qkv(const float* __restrict__ st,
                             const float* __restrict__ gq, const float* __restrict__ beq,
                             const float* __restrict__ gk, const float* __restrict__ bek,
                             const float* __restrict__ gv, const float* __restrict__ bev,
                             float* __restrict__ scv, float* __restrict__ shv)
{
  int c = threadIdx.x;
  const float inv = 1.0f / (float)RR;
  float mu  = st[c] * inv;
  float var = st[CQKV + c] * inv - mu * mu;
  const float *g, *be; int cl = c;
  if (c < 128)      { g = gq; be = beq; }
  else if (c < 256) { g = gk; be = bek; cl = c - 128; }
  else              { g = gv; be = bev; cl = c - 256; }
  float sc = g[cl] * rsqrtf(var + EPSB);
  float sh = be[cl] - mu * sc;
  if (c < 128) { sc *= 0.7213475204444817f; sh *= 0.7213475204444817f; }
  scv[c] = sc;
  shv[c] = sh;
}

// ------------------- norm+ReLU: K rows + V (chunk-major A-layout) ----------
// grid (384, 8). Kh: [bh][n][kk] row-major.
// Vt[bh][cidx(16)][dim(32)][quad(4)][j(8)] : element =
//   V[key = cidx*32 + (j>>2)*16 + quad*4 + (j&3)][dim]
// -> chunk-major so each PV A-fragment read in k_attn is one coalesced 1 KB
//    wave access; k-slot permutation matches P's natural register order.
__global__ __launch_bounds__(256) void k_norm_kv(
    const bf16* __restrict__ Y, const float* __restrict__ scv,
    const float* __restrict__ shv, bf16* __restrict__ Kh, bf16* __restrict__ Vt)
{
  __shared__ short vs[64][40];
  int t = threadIdx.x;
  int bh = blockIdx.x, nc = blockIdx.y;
  int bt = bh >> 2, h = bh & 3;
  int n0 = nc * 64;
  int r = t >> 2, cg = t & 3;
  // ---- K phase
  {
    int c = 128 + h * 32 + cg * 8;
    bf8_t y8 = *reinterpret_cast<const bf8_t*>(
        Y + ((size_t)bt * NN + n0 + r) * CQKV + c);
    bf8_t o8;
#pragma unroll
    for (int i = 0; i < 8; ++i)
      o8[i] = f2b(fmaxf(0.f, fmaf(b2f(y8[i]), scv[c + i], shv[c + i])));
    *reinterpret_cast<bf8_t*>(Kh + ((size_t)bh * NN + n0 + r) * 32 + cg * 8) = o8;
  }
  // ---- V phase (LDS transpose into permuted chunk-major A-layout)
  {
    int c = 256 + h * 32 + cg * 8;
    bf8_t y8 = *reinterpret_cast<const bf8_t*>(
        Y + ((size_t)bt * NN + n0 + r) * CQKV + c);
    bf8_t o8;
#pragma unroll
    for (int i = 0; i < 8; ++i)
      o8[i] = f2b(fmaxf(0.f, fmaf(b2f(y8[i]), scv[c + i], shv[c + i])));
    *reinterpret_cast<bf8_t*>(&vs[r][cg * 8]) = o8;
  }
  __syncthreads();
  int dim = t >> 3, kcl = (t >> 2) & 1, quad = t & 3;
  bf8_t w8;
#pragma unroll
  for (int j = 0; j < 8; ++j)
    w8[j] = vs[kcl * 32 + (j >> 2) * 16 + quad * 4 + (j & 3)][dim];
  *reinterpret_cast<bf8_t*>(Vt + (size_t)bh * 16384 +
                            (size_t)(nc * 2 + kcl) * 1024 + dim * 32 + quad * 8) = w8;
}

// ------------------- fused masked attention (max-free softmax) -------------
// grid 1536: bh = x % 384 (XCD-local), quarter = x / 384 (8 q-tiles each).
// S^T = MFMA(K, Q): lane owns query l16. Scores >= 0 (ReLU'd Q,K), folded
// base-2 exponent bounded ~30 << 126 -> max-free: p = masked ? 0 : exp2(s).
// Chunk loop capped at unroll 2 to bound in-flight V loads (VGPR pressure).
// NOTE: plain launch_bounds — (256,4) made the allocator spill (R10/R11).
__global__ __launch_bounds__(256) void k_attn(
    const bf16* __restrict__ Y, const float* __restrict__ scv,
    const float* __restrict__ shv, const bf16* __restrict__ Kh,
    const bf16* __restrict__ Vt, const unsigned int* __restrict__ Amb,
    bf16* __restrict__ AO)
{
  __shared__ __align__(16) bf16 KbS[512 * 32];     // 32 KB, rows 64B swizzled
  int tid = threadIdx.x;
  int wave = tid >> 6, lane = tid & 63;
  int quad = lane >> 4, l16 = lane & 15;
  int bh = blockIdx.x % 384;
  int quarter = blockIdx.x / 384;                  // q-tile quarter (0..3)
  int bt = bh >> 2, h = bh & 3;
  const char* Kp = (const char*)(Kh + (size_t)bh * NN * 32);
  const bf16* Vp = Vt + (size_t)bh * NN * 32;

  // ---- stage K with row-chunk swizzle
#pragma unroll
  for (int i = 0; i < 8; ++i) {
    int t2 = wave * 8 + i;
    int r = t2 * 16 + (lane >> 2);
    int p = (lane & 3) ^ ((r >> 1) & 3);
    gl_lds16(Kp + (size_t)r * 64 + p * 16, (char*)KbS + t2 * 1024 + lane * 16);
  }
  __syncthreads();

  const f32x4 zero = {0.f, 0.f, 0.f, 0.f};
#pragma unroll 1
  for (int it = 0; it < 2; ++it) {
    int nt = quarter * 8 + it * 4 + wave;          // global ntile 0..31
    int n0 = nt * 16;
    // Q inline norm+ReLU from Y: B-fragment (col=query l16, k=dim quad*8+j)
    int cq = h * 32 + quad * 8;
    bf8_t yq = *reinterpret_cast<const bf8_t*>(
        Y + ((size_t)bt * NN + n0 + l16) * CQKV + cq);
    bf8_t qf;
#pragma unroll
    for (int j = 0; j < 8; ++j)
      qf[j] = f2b(fmaxf(0.f, fmaf(b2f(yq[j]), scv[cq + j], shv[cq + j])));
    // mask words: query n0+l16, key-lane quad*4+rr, bit index = key tile
    unsigned int wm[4];
#pragma unroll
    for (int rr = 0; rr < 4; ++rr)
      wm[rr] = Amb[(size_t)(n0 + l16) * 16 + quad * 4 + rr];

    f32x4 o0 = zero, o1 = zero;                    // O^T dims 0-15 / 16-31
    float lrun = 0.f;

#pragma unroll 2
    for (int c = 0; c < 8; ++c) {
      // S^T chunk: 4 tiles x 16 keys; lane = (key quad*4+rr, query l16)
      f32x4 s[4];
#pragma unroll
      for (int mt = 0; mt < 4; ++mt) {
        int r = (c * 4 + mt) * 16 + l16;
        bf8_t kf = *reinterpret_cast<const bf8_t*>(
            (const char*)KbS + (size_t)r * 64 + ((quad ^ ((r >> 1) & 3)) * 16));
        s[mt] = MFMA16(kf, qf, zero);
      }
      // exp2 + mask->0 + partial sum + pack into PV B-fragments
      bf8_t f0, f1;
#pragma unroll
      for (int mt = 0; mt < 2; ++mt)
#pragma unroll
        for (int rr = 0; rr < 4; ++rr) {
          float p = ((wm[rr] >> (c * 4 + mt)) & 1u) ? fexp2(s[mt][rr]) : 0.f;
          lrun += p;
          f0[mt * 4 + rr] = f2b(p);
        }
#pragma unroll
      for (int mt = 2; mt < 4; ++mt)
#pragma unroll
        for (int rr = 0; rr < 4; ++rr) {
          float p = ((wm[rr] >> (c * 4 + mt)) & 1u) ? fexp2(s[mt][rr]) : 0.f;
          lrun += p;
          f1[(mt - 2) * 4 + rr] = f2b(p);
        }
      // PV: O^T += V^T_chunk . P^T_chunk  (Vt chunk-major: one coalesced 1 KB
      // wave read per fragment; chunks 2c/2c+1 = keys c*64..+31 / +32..+63)
      const bf16* va = Vp + (size_t)c * 2048 + l16 * 32 + quad * 8;
      o0 = MFMA16(*reinterpret_cast<const bf8_t*>(va),        f0, o0);
      o0 = MFMA16(*reinterpret_cast<const bf8_t*>(va + 1024), f1, o0);
      o1 = MFMA16(*reinterpret_cast<const bf8_t*>(va + 512),  f0, o1);
      o1 = MFMA16(*reinterpret_cast<const bf8_t*>(va + 1536), f1, o1);
    }
    // final: per-lane partial sums -> cross-quad total, divide (lane-local)
    lrun += __shfl_xor(lrun, 16);
    lrun += __shfl_xor(lrun, 32);
    float inv = 1.0f / lrun;
    unsigned int w0 = pk2(o0[0] * inv, o0[1] * inv);   // dims q*4+0, +1
    unsigned int w1 = pk2(o0[2] * inv, o0[3] * inv);   // dims q*4+2, +3
    unsigned int w2 = pk2(o1[0] * inv, o1[1] * inv);   // dims 16+q*4+0, +1
    unsigned int w3 = pk2(o1[2] * inv, o1[3] * inv);
    // butterfly: lane(quad,l16) gathers dims quad*8..+7 of its query l16
    int sL0 = (quad & 1) * 32 + l16;
    int sL1 = sL0 + 16;
    bool hi = quad >= 2;
    unsigned int a0 = __shfl(w0, sL0), b0 = __shfl(w2, sL0);
    unsigned int a1 = __shfl(w1, sL0), b1 = __shfl(w3, sL0);
    unsigned int a2 = __shfl(w0, sL1), b2 = __shfl(w2, sL1);
    unsigned int a3 = __shfl(w1, sL1), b3 = __shfl(w3, sL1);
    u32x4 ov = { hi ? b0 : a0, hi ? b1 : a1, hi ? b2 : a2, hi ? b3 : a3 };
    *reinterpret_cast<u32x4*>(
        AO + ((size_t)bt * NN + n0 + l16) * DD + h * 32 + quad * 8) = ov;
  }
}

// ------------------- final BN + ReLU ---------------------------------------
__global__ __launch_bounds__(256) void k_norm_o(
    const float* __restrict__ Yo, const float* __restrict__ st,
    const float* __restrict__ g, const float* __restrict__ be,
    float* __restrict__ out)
{
  int idx = blockIdx.x * 256 + threadIdx.x;      // < RR*128
  int c = idx & 127;
  const float inv = 1.0f / (float)RR;
  float mu  = st[c] * inv;
  float var = st[128 + c] * inv - mu * mu;
  float sc = g[c] * rsqrtf(var + EPSB);
  float sh = be[c] - mu * sc;
  out[idx] = fmaxf(0.f, fmaf(Yo[idx], sc, sh));
}

// ---------------------------------------------------------------------------
extern "C" void kernel_launch(void* const* d_in, const int* in_sizes, int n_in,
                              void* d_out, int out_size, void* d_ws, size_t ws_size,
                              hipStream_t stream)
{
  const float* X    = (const float*)d_in[0];
  const float* STE  = (const float*)d_in[1];
  const float* Am   = (const float*)d_in[2];
  const float* Wq   = (const float*)d_in[3];
  const float* gq   = (const float*)d_in[5];
  const float* beq  = (const float*)d_in[6];
  const float* Wk   = (const float*)d_in[7];
  const float* gk   = (const float*)d_in[9];
  const float* bek  = (const float*)d_in[10];
  const float* Wv   = (const float*)d_in[11];
  const float* gv   = (const float*)d_in[13];
  const float* bev  = (const float*)d_in[14];
  const float* Wo   = (const float*)d_in[15];
  const float* go   = (const float*)d_in[17];
  const float* beo  = (const float*)d_in[18];
  // biases d_in[4,8,12,16] unused: BN subtracts batch mean -> bias cancels.

  char* ws = (char*)d_ws;
  bf16*  Yqkv = (bf16*)(ws + 0);            // 37,748,736
  float* Yo   = (float*)(ws + 0);           // aliases Yqkv (dead after attn)
  bf16*  Xb   = (bf16*)(ws + 50331648);     // 25,165,824 — aliases Kh/Vt:
                                            //   dead before k_norm_kv runs
  bf16*  Kh   = (bf16*)(ws + 50331648);
  bf16*  Vt   = (bf16*)(ws + 62914560);
  bf16*  AO   = (bf16*)(ws + 75497472);
  bf16*  Wtq  = (bf16*)(ws + 88080384);     // 196,608
  bf16*  Wto  = (bf16*)(ws + 88276992);     // 32,768
  unsigned int* Amb = (unsigned int*)(ws + 88309760);  // 32,768
  float* st   = (float*)(ws + 88342528);    // [0,768) qkv | [768,1024) o
  float* stq  = st;
  float* sto  = st + 768;
  float* scv  = st + 1024;
  float* shv  = st + 1408;

  k_prep<<<6628, 256, 0, stream>>>(Wq, Wk, Wv, Wo, Am, X, STE,
                                   Wtq, Wto, Amb, st, Xb);
  k_gemm_qkv<<<dim3(RR / 128, 3), 256, 0, stream>>>(Xb, Wtq, Yqkv, stq);
  k_scales_qkv<<<1, CQKV, 0, stream>>>(stq, gq, beq, gk, bek, gv, bev, scv, shv);
  k_norm_kv<<<dim3(CQKV, 8), 256, 0, stream>>>(Yqkv, scv, shv, Kh, Vt);
  k_attn<<<1536, 256, 0, stream>>>(Yqkv, scv, shv, Kh, Vt, Amb, AO);
  k_gemm_o<<<dim3(RR / 128, 1), 256, 0, stream>>>(AO, Wto, Yo, sto);
  k_norm_o<<<(RR * 128) / 256, 256, 0, stream>>>(Yo, sto, go, beo, (float*)d_out);
}